// Round 1
// baseline (404.038 us; speedup 1.0000x reference)
//
#include <hip/hip_runtime.h>

typedef __bf16 bf16;
typedef __bf16 bf16x4 __attribute__((ext_vector_type(4)));
typedef __bf16 bf16x8 __attribute__((ext_vector_type(8)));
typedef float f32x4 __attribute__((ext_vector_type(4)));

__device__ __forceinline__ f32x4 MFMA16(bf16x8 a, bf16x8 b, f32x4 c) {
  return __builtin_amdgcn_mfma_f32_16x16x32_bf16(a, b, c, 0, 0, 0);
}

__device__ __forceinline__ bf16 split_hi(float v) { return (bf16)v; }
__device__ __forceinline__ bf16 split_lo(float v) { return (bf16)(v - (float)(bf16)v); }

// ---- f32 -> bf16 bulk convert ----
__global__ void k_cvt(const float* __restrict__ in, bf16* __restrict__ out, long n) {
  const long i = ((long)blockIdx.x * 256 + threadIdx.x) * 4;
  if (i < n) {
    const f32x4 v = *(const f32x4*)&in[i];
    bf16x4 o;
#pragma unroll
    for (int j = 0; j < 4; ++j) o[j] = (bf16)v[j];
    *(bf16x4*)&out[i] = o;
  }
}

// ---- Wc[b][d][r] = sum_k w[b,k] * neurons[idx[b,k]][d][r]  (f32 out) ----
__global__ void k_build_wc(const float* __restrict__ neurons, const float* __restrict__ w,
                           const int* __restrict__ idx, float* __restrict__ Wc) {
  const int d = blockIdx.x, b = blockIdx.y, r = threadIdx.x;
  float acc = 0.f;
#pragma unroll
  for (int k = 0; k < 16; ++k) {
    const float wk = w[b * 16 + k];
    const int ni = idx[b * 16 + k];
    acc += wk * neurons[((long)ni * 1024 + d) * 128 + r];
  }
  Wc[((long)b * 1024 + d) * 128 + r] = acc;
}

// ---- Wn[z=which*8+b][r][d] = sum_k w[b,k] * pool[idx[b,k]][r][d]  (f32 out) ----
__global__ void k_build_mix(const float* __restrict__ pool,
                            const float* __restrict__ wq, const int* __restrict__ iq,
                            const float* __restrict__ wk, const int* __restrict__ ik,
                            const float* __restrict__ wv, const int* __restrict__ iv,
                            float* __restrict__ Wn) {
  const int d = blockIdx.x * 256 + threadIdx.x;
  const int r = blockIdx.y;
  const int z = blockIdx.z, which = z >> 3, b = z & 7;
  const float* wp = which == 0 ? wq : (which == 1 ? wk : wv);
  const int* ip = which == 0 ? iq : (which == 1 ? ik : iv);
  float acc = 0.f;
#pragma unroll
  for (int k = 0; k < 8; ++k) {
    const float wkk = wp[b * 8 + k];
    const int ni = ip[b * 8 + k];
    acc += wkk * pool[((long)ni * 128 + r) * 1024 + d];
  }
  Wn[((long)z * 128 + r) * 1024 + d] = acc;
}

// ---- batched transpose f32 [M][N] -> split bf16 pair [N][M] ----
__global__ void k_transpose_split(const float* __restrict__ in, bf16* __restrict__ outh,
                                  bf16* __restrict__ outl, int M, int N) {
  __shared__ float t[64][65];
  const int n0 = blockIdx.x * 64, m0 = blockIdx.y * 64;
  const long base = (long)blockIdx.z * M * N;
  const int tid = threadIdx.x;
#pragma unroll
  for (int i = 0; i < 16; ++i) {
    const int lin = i * 256 + tid;
    const int r = lin >> 6, c = lin & 63;
    t[r][c] = in[base + (long)(m0 + r) * N + (n0 + c)];
  }
  __syncthreads();
#pragma unroll
  for (int i = 0; i < 16; ++i) {
    const int lin = i * 256 + tid;
    const int r = lin >> 6, c = lin & 63;
    const float v = t[c][r];
    const long off = base + (long)(n0 + r) * M + (m0 + c);
    outh[off] = split_hi(v);
    outl[off] = split_lo(v);
  }
}

// ---- h-GEMM: A f32 (split in-kernel), Bt pre-split bf16 pair; out split-pair.
// A [M][K] f32, Bt[n][k] pair. M=1024 N=128 K=1024. BM=BN=64, 4 waves 2x2.
__global__ __launch_bounds__(256) void k_gemm_h(
    const float* __restrict__ A, const bf16* __restrict__ Bth,
    const bf16* __restrict__ Btl, bf16* __restrict__ Ch, bf16* __restrict__ Cl,
    int M, int N, int K, long sA, long sB, long sC) {
  constexpr int LDR = 40;
  __shared__ __align__(16) bf16 Ash[64 * LDR], Asl[64 * LDR];
  __shared__ __align__(16) bf16 Bsh[64 * LDR], Bsl[64 * LDR];
  const int tid = threadIdx.x, wave = tid >> 6, lane = tid & 63;
  const int quad = lane >> 4, l16 = lane & 15;
  const int wrow = wave >> 1, wcol = wave & 1;
  const int z = blockIdx.z;
  const float* Ap = A + (long)z * sA;
  const bf16* Bph = Bth + (long)z * sB;
  const bf16* Bpl = Btl + (long)z * sB;
  const long m0 = (long)blockIdx.y * 64, n0 = (long)blockIdx.x * 64;
  f32x4 acc[2][2];
#pragma unroll
  for (int mt = 0; mt < 2; ++mt)
#pragma unroll
    for (int nt = 0; nt < 2; ++nt) acc[mt][nt] = (f32x4){0.f, 0.f, 0.f, 0.f};
  for (int k0 = 0; k0 < K; k0 += 32) {
#pragma unroll
    for (int i = 0; i < 2; ++i) {
      const int c = i * 256 + tid, r = c >> 3, c4 = c & 7;
      const f32x4 v = *(const f32x4*)&Ap[(m0 + r) * K + k0 + c4 * 4];
      bf16x4 h4, l4;
#pragma unroll
      for (int j = 0; j < 4; ++j) { h4[j] = split_hi(v[j]); l4[j] = split_lo(v[j]); }
      *(bf16x4*)&Ash[r * LDR + c4 * 4] = h4;
      *(bf16x4*)&Asl[r * LDR + c4 * 4] = l4;
    }
    {
      const int r = tid >> 2, c8 = tid & 3;
      *(bf16x8*)&Bsh[r * LDR + c8 * 8] = *(const bf16x8*)&Bph[(n0 + r) * K + k0 + c8 * 8];
      *(bf16x8*)&Bsl[r * LDR + c8 * 8] = *(const bf16x8*)&Bpl[(n0 + r) * K + k0 + c8 * 8];
    }
    __syncthreads();
    bf16x8 ah[2], al[2], bh[2], bl[2];
#pragma unroll
    for (int mt = 0; mt < 2; ++mt) {
      const int row = wrow * 32 + mt * 16 + l16;
      ah[mt] = *(const bf16x8*)&Ash[row * LDR + quad * 8];
      al[mt] = *(const bf16x8*)&Asl[row * LDR + quad * 8];
    }
#pragma unroll
    for (int nt = 0; nt < 2; ++nt) {
      const int row = wcol * 32 + nt * 16 + l16;
      bh[nt] = *(const bf16x8*)&Bsh[row * LDR + quad * 8];
      bl[nt] = *(const bf16x8*)&Bsl[row * LDR + quad * 8];
    }
#pragma unroll
    for (int mt = 0; mt < 2; ++mt)
#pragma unroll
      for (int nt = 0; nt < 2; ++nt) {
        acc[mt][nt] = MFMA16(ah[mt], bh[nt], acc[mt][nt]);
        acc[mt][nt] = MFMA16(ah[mt], bl[nt], acc[mt][nt]);
        acc[mt][nt] = MFMA16(al[mt], bh[nt], acc[mt][nt]);
      }
    __syncthreads();
  }
#pragma unroll
  for (int mt = 0; mt < 2; ++mt)
#pragma unroll
    for (int nt = 0; nt < 2; ++nt)
#pragma unroll
      for (int r = 0; r < 4; ++r) {
        const long row = m0 + wrow * 32 + mt * 16 + quad * 4 + r;
        const long col = n0 + wcol * 32 + nt * 16 + l16;
        const float v = acc[mt][nt][r];
        const long off = (long)z * sC + row * (long)N + col;
        const bf16 hi = (bf16)v;
        Ch[off] = hi;
        Cl[off] = (bf16)(v - (float)hi);
      }
}

// ---- dual-bf16 GEMM: A pair [M][K], Bt pair [N][K] (both pre-split).
// SPLIT: 3 MFMAs (hh+hl+lh); else hi-only, 1 MFMA.
// mode: 0 = bf16 out, 2 = split-pair out. split_heads: C[(col/64)][row][col%64].
template <bool SPLIT>
__global__ __launch_bounds__(256) void k_gemm_dual(
    const bf16* __restrict__ Ah, const bf16* __restrict__ Al,
    const bf16* __restrict__ Bth, const bf16* __restrict__ Btl,
    bf16* __restrict__ C, bf16* __restrict__ C2, int M, int N, int K,
    long sA, long sB, long sC, int split_heads, int mode, float scale) {
  constexpr int LDR = 40;
  __shared__ __align__(16) bf16 Ash[64 * LDR], Bsh[64 * LDR];
  __shared__ __align__(16) bf16 Asl[SPLIT ? 64 * LDR : 1];
  __shared__ __align__(16) bf16 Bsl[SPLIT ? 64 * LDR : 1];
  const int tid = threadIdx.x, wave = tid >> 6, lane = tid & 63;
  const int quad = lane >> 4, l16 = lane & 15;
  const int wrow = wave >> 1, wcol = wave & 1;
  const int z = blockIdx.z;
  const bf16* Aph = Ah + (long)z * sA;
  const bf16* Apl = Al + (long)z * sA;
  const bf16* Bph = Bth + (long)z * sB;
  const bf16* Bpl = Btl + (long)z * sB;
  const long m0 = (long)blockIdx.y * 64, n0 = (long)blockIdx.x * 64;
  f32x4 acc[2][2];
#pragma unroll
  for (int mt = 0; mt < 2; ++mt)
#pragma unroll
    for (int nt = 0; nt < 2; ++nt) acc[mt][nt] = (f32x4){0.f, 0.f, 0.f, 0.f};
  for (int k0 = 0; k0 < K; k0 += 32) {
    {
      const int r = tid >> 2, c8 = tid & 3;
      *(bf16x8*)&Ash[r * LDR + c8 * 8] = *(const bf16x8*)&Aph[(m0 + r) * K + k0 + c8 * 8];
      if (SPLIT)
        *(bf16x8*)&Asl[r * LDR + c8 * 8] = *(const bf16x8*)&Apl[(m0 + r) * K + k0 + c8 * 8];
      *(bf16x8*)&Bsh[r * LDR + c8 * 8] = *(const bf16x8*)&Bph[(n0 + r) * K + k0 + c8 * 8];
      if (SPLIT)
        *(bf16x8*)&Bsl[r * LDR + c8 * 8] = *(const bf16x8*)&Bpl[(n0 + r) * K + k0 + c8 * 8];
    }
    __syncthreads();
    bf16x8 ah[2], al[2], bh[2], bl[2];
#pragma unroll
    for (int mt = 0; mt < 2; ++mt) {
      const int row = wrow * 32 + mt * 16 + l16;
      ah[mt] = *(const bf16x8*)&Ash[row * LDR + quad * 8];
      if (SPLIT) al[mt] = *(const bf16x8*)&Asl[row * LDR + quad * 8];
    }
#pragma unroll
    for (int nt = 0; nt < 2; ++nt) {
      const int row = wcol * 32 + nt * 16 + l16;
      bh[nt] = *(const bf16x8*)&Bsh[row * LDR + quad * 8];
      if (SPLIT) bl[nt] = *(const bf16x8*)&Bsl[row * LDR + quad * 8];
    }
#pragma unroll
    for (int mt = 0; mt < 2; ++mt)
#pragma unroll
      for (int nt = 0; nt < 2; ++nt) {
        acc[mt][nt] = MFMA16(ah[mt], bh[nt], acc[mt][nt]);
        if (SPLIT) {
          acc[mt][nt] = MFMA16(ah[mt], bl[nt], acc[mt][nt]);
          acc[mt][nt] = MFMA16(al[mt], bh[nt], acc[mt][nt]);
        }
      }
    __syncthreads();
  }
#pragma unroll
  for (int mt = 0; mt < 2; ++mt)
#pragma unroll
    for (int nt = 0; nt < 2; ++nt)
#pragma unroll
      for (int r = 0; r < 4; ++r) {
        const long row = m0 + wrow * 32 + mt * 16 + quad * 4 + r;
        const long col = n0 + wcol * 32 + nt * 16 + l16;
        const float v = acc[mt][nt][r] * scale;
        const long off = (long)z * sC +
                         (split_heads ? ((col >> 6) * ((long)M * 64) + row * 64 + (col & 63))
                                      : (row * (long)N + col));
        if (mode == 2) {
          const bf16 hi = (bf16)v;
          C[off] = hi;
          C2[off] = (bf16)(v - (float)hi);
        } else {
          C[off] = (bf16)v;
        }
      }
}

// ---- plain bf16 GEMM (output projection): C = A(MxK) * Bt[n][k], out f32. ----
template <int BM, int BN>
__global__ __launch_bounds__(256) void k_gemm_bt(
    const bf16* __restrict__ A, const bf16* __restrict__ Bt, float* __restrict__ C,
    int M, int N, int K) {
  constexpr int BK = 32, LDR = BK + 8;
  constexpr int MT = BM / 32, NT = BN / 32;
  __shared__ __align__(16) bf16 As[BM * LDR];
  __shared__ __align__(16) bf16 Bs[BN * LDR];
  const int tid = threadIdx.x, wave = tid >> 6, lane = tid & 63;
  const int quad = lane >> 4, l16 = lane & 15;
  const int wrow = wave >> 1, wcol = wave & 1;
  const long m0 = (long)blockIdx.y * BM, n0 = (long)blockIdx.x * BN;
  f32x4 acc[MT][NT];
#pragma unroll
  for (int mt = 0; mt < MT; ++mt)
#pragma unroll
    for (int nt = 0; nt < NT; ++nt) acc[mt][nt] = (f32x4){0.f, 0.f, 0.f, 0.f};
  constexpr int ACH = BM * BK / 8 / 256;
  constexpr int BCH = BN * BK / 8 / 256;
  for (int k0 = 0; k0 < K; k0 += BK) {
#pragma unroll
    for (int i = 0; i < ACH; ++i) {
      const int c = i * 256 + tid, r = c >> 2, c4 = c & 3;
      *(bf16x8*)&As[r * LDR + c4 * 8] = *(const bf16x8*)&A[(m0 + r) * K + k0 + c4 * 8];
    }
#pragma unroll
    for (int i = 0; i < BCH; ++i) {
      const int c = i * 256 + tid, r = c >> 2, c4 = c & 3;
      *(bf16x8*)&Bs[r * LDR + c4 * 8] = *(const bf16x8*)&Bt[(n0 + r) * K + k0 + c4 * 8];
    }
    __syncthreads();
    bf16x8 af[MT], bfr[NT];
#pragma unroll
    for (int mt = 0; mt < MT; ++mt)
      af[mt] = *(const bf16x8*)&As[(wrow * MT * 16 + mt * 16 + l16) * LDR + quad * 8];
#pragma unroll
    for (int nt = 0; nt < NT; ++nt)
      bfr[nt] = *(const bf16x8*)&Bs[(wcol * NT * 16 + nt * 16 + l16) * LDR + quad * 8];
#pragma unroll
    for (int mt = 0; mt < MT; ++mt)
#pragma unroll
      for (int nt = 0; nt < NT; ++nt)
        acc[mt][nt] = MFMA16(af[mt], bfr[nt], acc[mt][nt]);
    __syncthreads();
  }
#pragma unroll
  for (int mt = 0; mt < MT; ++mt)
#pragma unroll
    for (int nt = 0; nt < NT; ++nt)
#pragma unroll
      for (int r = 0; r < 4; ++r) {
        const long row = m0 + wrow * MT * 16 + mt * 16 + quad * 4 + r;
        const long col = n0 + wcol * NT * 16 + nt * 16 + l16;
        C[row * (long)N + col] = acc[mt][nt][r];
      }
}

// ---- causal flash attention, 8-wave blocks: waves 0-3 -> q-block p, waves 4-7
// -> q-block 7-p (causal balance preserved inside the block). One 32-row strip
// per wave halves persistent VGPR state vs the old per-wave A+B pairing;
// __launch_bounds__(512,4) forces <=128 VGPR -> 2 blocks (16 waves) per CU.
// K/V LDS (double-buffered, reg-prefetched) now shared by 8 waves. Ps is a
// 16-row per-wave slice (both m-subtiles reuse it; read happens in the same m
// iteration) with stride 88 (176 B): quad-stride 704 % 128 = 64 -> 2-way write
// conflict instead of 4-way at stride 72.
__global__ __launch_bounds__(512, 4) void k_attn(
    const bf16* __restrict__ Qhi, const bf16* __restrict__ Qlo,
    const bf16* __restrict__ Khi, const bf16* __restrict__ Klo,
    const bf16* __restrict__ Vtg, bf16* __restrict__ Og) {
  __shared__ __align__(16) bf16 KhiS[2 * 64 * 72], KloS[2 * 64 * 72];
  __shared__ __align__(16) bf16 VtS[2 * 64 * 72];
  __shared__ __align__(16) bf16 Ps[8 * 16 * 88];
  const int p = blockIdx.x, bh = blockIdx.y;
  const int b = bh >> 4, hh = bh & 15;
  const int tid = threadIdx.x, wave = tid >> 6, lane = tid & 63;
  const int quad = lane >> 4, l16 = lane & 15;
  const long bhS = (long)bh * 1024 * 64;
  const bf16* KhiG = Khi + bhS;
  const bf16* KloG = Klo + bhS;
  const bf16* VtG = Vtg + (long)bh * 64 * 1024;
  const int qb = (wave < 4) ? p : (7 - p);
  const int qbw = qb * 128 + (wave & 3) * 32;
  bf16* myPs = &Ps[wave * 16 * 88];
  bf16x8 qh[2][2], ql[2][2];
#pragma unroll
  for (int m = 0; m < 2; ++m) {
    const long rq = (long)(qbw + m * 16 + l16) * 64;
#pragma unroll
    for (int s = 0; s < 2; ++s) {
      qh[m][s] = *(const bf16x8*)&Qhi[bhS + rq + s * 32 + quad * 8];
      ql[m][s] = *(const bf16x8*)&Qlo[bhS + rq + s * 32 + quad * 8];
    }
  }
  bf16x8 ones8;
#pragma unroll
  for (int j = 0; j < 8; ++j) ones8[j] = (bf16)1.0f;
  const f32x4 zero4 = {0.f, 0.f, 0.f, 0.f};
  f32x4 o[2][4];
  float m_i[2][4], l_i[2][4];
#pragma unroll
  for (int m = 0; m < 2; ++m)
#pragma unroll
    for (int r = 0; r < 4; ++r) { m_i[m][r] = -1.0e30f; l_i[m][r] = 0.f; }
#pragma unroll
  for (int m = 0; m < 2; ++m)
#pragma unroll
    for (int nt = 0; nt < 4; ++nt) o[m][nt] = zero4;

  // staging: 512 threads cover one 64x64 bf16 chunk per array (1 bf16x8 each)
  const int sr = tid >> 3, sc8 = tid & 7;
  bf16x8 sKh, sKl, sVt;
  auto load_regs = [&](int kc) {
    const int kb = kc * 64;
    sKh = *(const bf16x8*)&KhiG[(long)(kb + sr) * 64 + sc8 * 8];
    sKl = *(const bf16x8*)&KloG[(long)(kb + sr) * 64 + sc8 * 8];
    sVt = *(const bf16x8*)&VtG[(long)sr * 1024 + kb + sc8 * 8];
  };
  auto write_lds = [&](int buf) {
    const int ob = buf * 64 * 72;
    *(bf16x8*)&KhiS[ob + sr * 72 + sc8 * 8] = sKh;
    *(bf16x8*)&KloS[ob + sr * 72 + sc8 * 8] = sKl;
    *(bf16x8*)&VtS[ob + sr * 72 + sc8 * 8] = sVt;
  };
  auto tile_compute = [&](int kb, int buf) {
    const int ob = buf * 64 * 72;
    f32x4 sc[2][4];
    __builtin_amdgcn_s_setprio(1);
#pragma unroll
    for (int ct = 0; ct < 4; ++ct) {
      const int krow = ob + (ct * 16 + l16) * 72;
      const bf16x8 kh0 = *(const bf16x8*)&KhiS[krow + quad * 8];
      const bf16x8 kh1 = *(const bf16x8*)&KhiS[krow + 32 + quad * 8];
      const bf16x8 kl0 = *(const bf16x8*)&KloS[krow + quad * 8];
      const bf16x8 kl1 = *(const bf16x8*)&KloS[krow + 32 + quad * 8];
#pragma unroll
      for (int m = 0; m < 2; ++m) {
        f32x4 s = MFMA16(qh[m][0], kh0, zero4);
        s = MFMA16(qh[m][1], kh1, s);
        s = MFMA16(qh[m][0], kl0, s);
        s = MFMA16(qh[m][1], kl1, s);
        s = MFMA16(ql[m][0], kh0, s);
        s = MFMA16(ql[m][1], kh1, s);
        sc[m][ct] = s;
      }
    }
    __builtin_amdgcn_s_setprio(0);
    if (kb + 63 > qbw) {
#pragma unroll
      for (int ct = 0; ct < 4; ++ct) {
        const int col = kb + ct * 16 + l16;
#pragma unroll
        for (int m = 0; m < 2; ++m)
#pragma unroll
          for (int r = 0; r < 4; ++r) {
            const int row = qbw + m * 16 + quad * 4 + r;
            if (col > row) sc[m][ct][r] = -1.0e30f;
          }
      }
    }
    bf16x8 ap[2][2];
    float alpha[2][4];
#pragma unroll
    for (int m = 0; m < 2; ++m) {
      float rmax[4];
#pragma unroll
      for (int r = 0; r < 4; ++r)
        rmax[r] = fmaxf(fmaxf(sc[m][0][r], sc[m][1][r]), fmaxf(sc[m][2][r], sc[m][3][r]));
#pragma unroll
      for (int off = 1; off < 16; off <<= 1)
#pragma unroll
        for (int r = 0; r < 4; ++r) rmax[r] = fmaxf(rmax[r], __shfl_xor(rmax[r], off));
#pragma unroll
      for (int r = 0; r < 4; ++r) {
        const float mnew = fmaxf(m_i[m][r], rmax[r]);
        alpha[m][r] = __builtin_amdgcn_exp2f(m_i[m][r] - mnew);
        m_i[m][r] = mnew;
      }
#pragma unroll
      for (int ct = 0; ct < 4; ++ct)
#pragma unroll
        for (int r = 0; r < 4; ++r)
          myPs[(quad * 4 + r) * 88 + ct * 16 + l16] =
              (bf16)__builtin_amdgcn_exp2f(sc[m][ct][r] - m_i[m][r]);
      ap[m][0] = *(const bf16x8*)&myPs[l16 * 88 + quad * 8];
      ap[m][1] = *(const bf16x8*)&myPs[l16 * 88 + 32 + quad * 8];
      f32x4 rs = MFMA16(ap[m][0], ones8, zero4);
      rs = MFMA16(ap[m][1], ones8, rs);
#pragma unroll
      for (int r = 0; r < 4; ++r) l_i[m][r] = l_i[m][r] * alpha[m][r] + rs[r];
#pragma unroll
      for (int nt = 0; nt < 4; ++nt)
#pragma unroll
        for (int r = 0; r < 4; ++r) o[m][nt][r] *= alpha[m][r];
    }
    __builtin_amdgcn_s_setprio(1);
#pragma unroll
    for (int nt = 0; nt < 4; ++nt) {
      const bf16x8 bv0 = *(const bf16x8*)&VtS[ob + (nt * 16 + l16) * 72 + quad * 8];
      const bf16x8 bv1 = *(const bf16x8*)&VtS[ob + (nt * 16 + l16) * 72 + 32 + quad * 8];
#pragma unroll
      for (int m = 0; m < 2; ++m) {
        o[m][nt] = MFMA16(ap[m][0], bv0, o[m][nt]);
        o[m][nt] = MFMA16(ap[m][1], bv1, o[m][nt]);
      }
    }
    __builtin_amdgcn_s_setprio(0);
  };

  const int nch = 2 * (7 - p) + 2;
  load_regs(0);
  write_lds(0);
  __syncthreads();
  for (int kc = 0; kc < nch; ++kc) {
    const int kb = kc * 64;
    const int buf = kc & 1;
    if (kc + 1 < nch) load_regs(kc + 1);
    if (kb <= qbw + 31) tile_compute(kb, buf);
    if (kc + 1 < nch) write_lds(1 - buf);
    __syncthreads();
  }
#pragma unroll
  for (int m = 0; m < 2; ++m) {
    float inv[4];
#pragma unroll
    for (int r = 0; r < 4; ++r) inv[r] = 1.f / l_i[m][r];
#pragma unroll
    for (int nt = 0; nt < 4; ++nt)
#pragma unroll
      for (int r = 0; r < 4; ++r) {
        const int row = qbw + m * 16 + quad * 4 + r;
        Og[((long)b * 1024 + row) * 1024 + hh * 64 + nt * 16 + l16] =
            (bf16)(o[m][nt][r] * inv[r]);
      }
  }
}

extern "C" void kernel_launch(void* const* d_in, const int* in_sizes, int n_in,
                              void* d_out, int out_size, void* d_ws, size_t ws_size,
                              hipStream_t stream) {
  const float* x = (const float*)d_in[0];
  const float* cw = (const float*)d_in[1];
  const int* cidx = (const int*)d_in[2];
  const float* wq = (const float*)d_in[3];
  const int* iq = (const int*)d_in[4];
  const float* wk = (const float*)d_in[5];
  const int* ik = (const int*)d_in[6];
  const float* wv = (const float*)d_in[7];
  const int* iv = (const int*)d_in[8];
  const float* neurons = (const float*)d_in[9];
  const float* pool = (const float*)d_in[10];
  const float* WO = (const float*)d_in[11];
  float* out = (float*)d_out;
  char* ws = (char*)d_ws;
  // Workspace (86 MB peak, lifetime-overlapped):
  //   [ 0,16) Khi | [16,32) Klo | [32,48) Vt (all bf16)
  //   [48,64) att bf16 -- prep overlay: Wc f32 [48,52), Wn f32 [52,64)
  //   [64,66) WcTh | [66,68) WcTl   bf16 [8][128][1024]
  //   [68,74) Wth  | [74,80) Wtl    bf16 [24][1024][128]
  //   [80,82) hh   | [82,84) hl     bf16 [8][1024][128]
  //   [84,86) WOb bf16
  //   Qhi/Qlo bf16 in d_out (2 x 16 MB), dead before the final f32 write.
  bf16* Khi = (bf16*)(ws + (0l << 20));
  bf16* Klo = (bf16*)(ws + (16l << 20));
  bf16* Vt = (bf16*)(ws + (32l << 20));
  bf16* att = (bf16*)(ws + (48l << 20));
  float* Wc = (float*)(ws + (48l << 20));
  float* Wn = (float*)(ws + (52l << 20));
  bf16* WcTh = (bf16*)(ws + (64l << 20));
  bf16* WcTl = (bf16*)(ws + (66l << 20));
  bf16* Wth = (bf16*)(ws + (68l << 20));
  bf16* Wtl = (bf16*)(ws + (74l << 20));
  bf16* hh = (bf16*)(ws + (80l << 20));
  bf16* hl = (bf16*)(ws + (82l << 20));
  bf16* WOb = (bf16*)(ws + (84l << 20));
  bf16* Qhi = (bf16*)d_out;
  bf16* Qlo = (bf16*)d_out + (8l << 20);

  k_cvt<<<1024, 256, 0, stream>>>(WO, WOb, 1024l * 1024);
  k_build_wc<<<dim3(1024, 8), 128, 0, stream>>>(neurons, cw, cidx, Wc);
  k_build_mix<<<dim3(4, 128, 24), 256, 0, stream>>>(pool, wq, iq, wk, ik, wv, iv, Wn);
  k_transpose_split<<<dim3(2, 16, 8), 256, 0, stream>>>(Wc, WcTh, WcTl, 1024, 128);
  k_transpose_split<<<dim3(16, 2, 24), 256, 0, stream>>>(Wn, Wth, Wtl, 128, 1024);
  // h = x * Wc (split A in-kernel, dual B), out split-pair hh/hl [8][1024][128]
  k_gemm_h<<<dim3(2, 16, 8), 256, 0, stream>>>(
      x, WcTh, WcTl, hh, hl, 1024, 128, 1024, 1l << 20, 1l << 17, 1l << 17);
  // Q = (h*Wq) * (log2e/8), split-pair out, head-split
  k_gemm_dual<true><<<dim3(16, 16, 8), 256, 0, stream>>>(
      hh, hl, Wth, Wtl, Qhi, Qlo, 1024, 1024, 128, 1l << 17, 1l << 17, 1l << 20,
      1, 2, 0.125f * 1.44269504088896f);
  // K split-pair out, head-split
  k_gemm_dual<true><<<dim3(16, 16, 8), 256, 0, stream>>>(
      hh, hl, Wth + (8l << 17), Wtl + (8l << 17), Khi, Klo, 1024, 1024, 128,
      1l << 17, 1l << 17, 1l << 20, 1, 2, 1.f);
  // V^T: A=Wt_V (hi only), B=h (hi only), plain bf16 out [b][d][s]
  k_gemm_dual<false><<<dim3(16, 16, 8), 256, 0, stream>>>(
      Wth + (16l << 17), nullptr, hh, nullptr, Vt, nullptr, 1024, 1024, 128,
      1l << 17, 1l << 17, 1l << 20, 0, 0, 1.f);
  k_attn<<<dim3(4, 128), 512, 0, stream>>>(Qhi, Qlo, Khi, Klo, Vt, att);
  // out(f32, 8192x1024) = att * W_O^T
  k_gemm_bt<128, 128><<<dim3(8, 64, 1), 256, 0, stream>>>(att, WOb, out, 8192, 1024, 1024);
}

// Round 3
// 380.144 us; speedup vs baseline: 1.0629x; 1.0629x over previous
//
#include <hip/hip_runtime.h>

typedef __bf16 bf16;
typedef __bf16 bf16x4 __attribute__((ext_vector_type(4)));
typedef __bf16 bf16x8 __attribute__((ext_vector_type(8)));
typedef float f32x4 __attribute__((ext_vector_type(4)));

__device__ __forceinline__ f32x4 MFMA16(bf16x8 a, bf16x8 b, f32x4 c) {
  return __builtin_amdgcn_mfma_f32_16x16x32_bf16(a, b, c, 0, 0, 0);
}

__device__ __forceinline__ bf16 split_hi(float v) { return (bf16)v; }
__device__ __forceinline__ bf16 split_lo(float v) { return (bf16)(v - (float)(bf16)v); }

// ---- f32 -> bf16 bulk convert ----
__global__ void k_cvt(const float* __restrict__ in, bf16* __restrict__ out, long n) {
  const long i = ((long)blockIdx.x * 256 + threadIdx.x) * 4;
  if (i < n) {
    const f32x4 v = *(const f32x4*)&in[i];
    bf16x4 o;
#pragma unroll
    for (int j = 0; j < 4; ++j) o[j] = (bf16)v[j];
    *(bf16x4*)&out[i] = o;
  }
}

// ---- Wc[b][d][r] = sum_k w[b,k] * neurons[idx[b,k]][d][r]  (f32 out) ----
__global__ void k_build_wc(const float* __restrict__ neurons, const float* __restrict__ w,
                           const int* __restrict__ idx, float* __restrict__ Wc) {
  const int d = blockIdx.x, b = blockIdx.y, r = threadIdx.x;
  float acc = 0.f;
#pragma unroll
  for (int k = 0; k < 16; ++k) {
    const float wk = w[b * 16 + k];
    const int ni = idx[b * 16 + k];
    acc += wk * neurons[((long)ni * 1024 + d) * 128 + r];
  }
  Wc[((long)b * 1024 + d) * 128 + r] = acc;
}

// ---- Wn[z=which*8+b][r][d] = sum_k w[b,k] * pool[idx[b,k]][r][d]  (f32 out) ----
__global__ void k_build_mix(const float* __restrict__ pool,
                            const float* __restrict__ wq, const int* __restrict__ iq,
                            const float* __restrict__ wk, const int* __restrict__ ik,
                            const float* __restrict__ wv, const int* __restrict__ iv,
                            float* __restrict__ Wn) {
  const int d = blockIdx.x * 256 + threadIdx.x;
  const int r = blockIdx.y;
  const int z = blockIdx.z, which = z >> 3, b = z & 7;
  const float* wp = which == 0 ? wq : (which == 1 ? wk : wv);
  const int* ip = which == 0 ? iq : (which == 1 ? ik : iv);
  float acc = 0.f;
#pragma unroll
  for (int k = 0; k < 8; ++k) {
    const float wkk = wp[b * 8 + k];
    const int ni = ip[b * 8 + k];
    acc += wkk * pool[((long)ni * 128 + r) * 1024 + d];
  }
  Wn[((long)z * 128 + r) * 1024 + d] = acc;
}

// ---- batched transpose f32 [M][N] -> split bf16 pair [N][M] ----
__global__ void k_transpose_split(const float* __restrict__ in, bf16* __restrict__ outh,
                                  bf16* __restrict__ outl, int M, int N) {
  __shared__ float t[64][65];
  const int n0 = blockIdx.x * 64, m0 = blockIdx.y * 64;
  const long base = (long)blockIdx.z * M * N;
  const int tid = threadIdx.x;
#pragma unroll
  for (int i = 0; i < 16; ++i) {
    const int lin = i * 256 + tid;
    const int r = lin >> 6, c = lin & 63;
    t[r][c] = in[base + (long)(m0 + r) * N + (n0 + c)];
  }
  __syncthreads();
#pragma unroll
  for (int i = 0; i < 16; ++i) {
    const int lin = i * 256 + tid;
    const int r = lin >> 6, c = lin & 63;
    const float v = t[c][r];
    const long off = base + (long)(n0 + r) * M + (m0 + c);
    outh[off] = split_hi(v);
    outl[off] = split_lo(v);
  }
}

// ---- h-GEMM: A f32 (split in-kernel), Bt pre-split bf16 pair; out split-pair.
// A [M][K] f32, Bt[n][k] pair. M=1024 N=128 K=1024. BM=BN=64, 4 waves 2x2.
__global__ __launch_bounds__(256) void k_gemm_h(
    const float* __restrict__ A, const bf16* __restrict__ Bth,
    const bf16* __restrict__ Btl, bf16* __restrict__ Ch, bf16* __restrict__ Cl,
    int M, int N, int K, long sA, long sB, long sC) {
  constexpr int LDR = 40;
  __shared__ __align__(16) bf16 Ash[64 * LDR], Asl[64 * LDR];
  __shared__ __align__(16) bf16 Bsh[64 * LDR], Bsl[64 * LDR];
  const int tid = threadIdx.x, wave = tid >> 6, lane = tid & 63;
  const int quad = lane >> 4, l16 = lane & 15;
  const int wrow = wave >> 1, wcol = wave & 1;
  const int z = blockIdx.z;
  const float* Ap = A + (long)z * sA;
  const bf16* Bph = Bth + (long)z * sB;
  const bf16* Bpl = Btl + (long)z * sB;
  const long m0 = (long)blockIdx.y * 64, n0 = (long)blockIdx.x * 64;
  f32x4 acc[2][2];
#pragma unroll
  for (int mt = 0; mt < 2; ++mt)
#pragma unroll
    for (int nt = 0; nt < 2; ++nt) acc[mt][nt] = (f32x4){0.f, 0.f, 0.f, 0.f};
  for (int k0 = 0; k0 < K; k0 += 32) {
#pragma unroll
    for (int i = 0; i < 2; ++i) {
      const int c = i * 256 + tid, r = c >> 3, c4 = c & 7;
      const f32x4 v = *(const f32x4*)&Ap[(m0 + r) * K + k0 + c4 * 4];
      bf16x4 h4, l4;
#pragma unroll
      for (int j = 0; j < 4; ++j) { h4[j] = split_hi(v[j]); l4[j] = split_lo(v[j]); }
      *(bf16x4*)&Ash[r * LDR + c4 * 4] = h4;
      *(bf16x4*)&Asl[r * LDR + c4 * 4] = l4;
    }
    {
      const int r = tid >> 2, c8 = tid & 3;
      *(bf16x8*)&Bsh[r * LDR + c8 * 8] = *(const bf16x8*)&Bph[(n0 + r) * K + k0 + c8 * 8];
      *(bf16x8*)&Bsl[r * LDR + c8 * 8] = *(const bf16x8*)&Bpl[(n0 + r) * K + k0 + c8 * 8];
    }
    __syncthreads();
    bf16x8 ah[2], al[2], bh[2], bl[2];
#pragma unroll
    for (int mt = 0; mt < 2; ++mt) {
      const int row = wrow * 32 + mt * 16 + l16;
      ah[mt] = *(const bf16x8*)&Ash[row * LDR + quad * 8];
      al[mt] = *(const bf16x8*)&Asl[row * LDR + quad * 8];
    }
#pragma unroll
    for (int nt = 0; nt < 2; ++nt) {
      const int row = wcol * 32 + nt * 16 + l16;
      bh[nt] = *(const bf16x8*)&Bsh[row * LDR + quad * 8];
      bl[nt] = *(const bf16x8*)&Bsl[row * LDR + quad * 8];
    }
#pragma unroll
    for (int mt = 0; mt < 2; ++mt)
#pragma unroll
      for (int nt = 0; nt < 2; ++nt) {
        acc[mt][nt] = MFMA16(ah[mt], bh[nt], acc[mt][nt]);
        acc[mt][nt] = MFMA16(ah[mt], bl[nt], acc[mt][nt]);
        acc[mt][nt] = MFMA16(al[mt], bh[nt], acc[mt][nt]);
      }
    __syncthreads();
  }
#pragma unroll
  for (int mt = 0; mt < 2; ++mt)
#pragma unroll
    for (int nt = 0; nt < 2; ++nt)
#pragma unroll
      for (int r = 0; r < 4; ++r) {
        const long row = m0 + wrow * 32 + mt * 16 + quad * 4 + r;
        const long col = n0 + wcol * 32 + nt * 16 + l16;
        const float v = acc[mt][nt][r];
        const long off = (long)z * sC + row * (long)N + col;
        const bf16 hi = (bf16)v;
        Ch[off] = hi;
        Cl[off] = (bf16)(v - (float)hi);
      }
}

// ---- dual-bf16 GEMM: A pair [M][K], Bt pair [N][K] (both pre-split).
// SPLIT: 3 MFMAs (hh+hl+lh); else hi-only, 1 MFMA.
// mode: 0 = bf16 out, 2 = split-pair out. split_heads: C[(col/64)][row][col%64].
template <bool SPLIT>
__global__ __launch_bounds__(256) void k_gemm_dual(
    const bf16* __restrict__ Ah, const bf16* __restrict__ Al,
    const bf16* __restrict__ Bth, const bf16* __restrict__ Btl,
    bf16* __restrict__ C, bf16* __restrict__ C2, int M, int N, int K,
    long sA, long sB, long sC, int split_heads, int mode, float scale) {
  constexpr int LDR = 40;
  __shared__ __align__(16) bf16 Ash[64 * LDR], Bsh[64 * LDR];
  __shared__ __align__(16) bf16 Asl[SPLIT ? 64 * LDR : 1];
  __shared__ __align__(16) bf16 Bsl[SPLIT ? 64 * LDR : 1];
  const int tid = threadIdx.x, wave = tid >> 6, lane = tid & 63;
  const int quad = lane >> 4, l16 = lane & 15;
  const int wrow = wave >> 1, wcol = wave & 1;
  const int z = blockIdx.z;
  const bf16* Aph = Ah + (long)z * sA;
  const bf16* Apl = Al + (long)z * sA;
  const bf16* Bph = Bth + (long)z * sB;
  const bf16* Bpl = Btl + (long)z * sB;
  const long m0 = (long)blockIdx.y * 64, n0 = (long)blockIdx.x * 64;
  f32x4 acc[2][2];
#pragma unroll
  for (int mt = 0; mt < 2; ++mt)
#pragma unroll
    for (int nt = 0; nt < 2; ++nt) acc[mt][nt] = (f32x4){0.f, 0.f, 0.f, 0.f};
  for (int k0 = 0; k0 < K; k0 += 32) {
    {
      const int r = tid >> 2, c8 = tid & 3;
      *(bf16x8*)&Ash[r * LDR + c8 * 8] = *(const bf16x8*)&Aph[(m0 + r) * K + k0 + c8 * 8];
      if (SPLIT)
        *(bf16x8*)&Asl[r * LDR + c8 * 8] = *(const bf16x8*)&Apl[(m0 + r) * K + k0 + c8 * 8];
      *(bf16x8*)&Bsh[r * LDR + c8 * 8] = *(const bf16x8*)&Bph[(n0 + r) * K + k0 + c8 * 8];
      if (SPLIT)
        *(bf16x8*)&Bsl[r * LDR + c8 * 8] = *(const bf16x8*)&Bpl[(n0 + r) * K + k0 + c8 * 8];
    }
    __syncthreads();
    bf16x8 ah[2], al[2], bh[2], bl[2];
#pragma unroll
    for (int mt = 0; mt < 2; ++mt) {
      const int row = wrow * 32 + mt * 16 + l16;
      ah[mt] = *(const bf16x8*)&Ash[row * LDR + quad * 8];
      if (SPLIT) al[mt] = *(const bf16x8*)&Asl[row * LDR + quad * 8];
    }
#pragma unroll
    for (int nt = 0; nt < 2; ++nt) {
      const int row = wcol * 32 + nt * 16 + l16;
      bh[nt] = *(const bf16x8*)&Bsh[row * LDR + quad * 8];
      if (SPLIT) bl[nt] = *(const bf16x8*)&Bsl[row * LDR + quad * 8];
    }
#pragma unroll
    for (int mt = 0; mt < 2; ++mt)
#pragma unroll
      for (int nt = 0; nt < 2; ++nt) {
        acc[mt][nt] = MFMA16(ah[mt], bh[nt], acc[mt][nt]);
        if (SPLIT) {
          acc[mt][nt] = MFMA16(ah[mt], bl[nt], acc[mt][nt]);
          acc[mt][nt] = MFMA16(al[mt], bh[nt], acc[mt][nt]);
        }
      }
    __syncthreads();
  }
#pragma unroll
  for (int mt = 0; mt < 2; ++mt)
#pragma unroll
    for (int nt = 0; nt < 2; ++nt)
#pragma unroll
      for (int r = 0; r < 4; ++r) {
        const long row = m0 + wrow * 32 + mt * 16 + quad * 4 + r;
        const long col = n0 + wcol * 32 + nt * 16 + l16;
        const float v = acc[mt][nt][r] * scale;
        const long off = (long)z * sC +
                         (split_heads ? ((col >> 6) * ((long)M * 64) + row * 64 + (col & 63))
                                      : (row * (long)N + col));
        if (mode == 2) {
          const bf16 hi = (bf16)v;
          C[off] = hi;
          C2[off] = (bf16)(v - (float)hi);
        } else {
          C[off] = (bf16)v;
        }
      }
}

// ---- plain bf16 GEMM (output projection): C = A(MxK) * Bt[n][k], out f32. ----
template <int BM, int BN>
__global__ __launch_bounds__(256) void k_gemm_bt(
    const bf16* __restrict__ A, const bf16* __restrict__ Bt, float* __restrict__ C,
    int M, int N, int K) {
  constexpr int BK = 32, LDR = BK + 8;
  constexpr int MT = BM / 32, NT = BN / 32;
  __shared__ __align__(16) bf16 As[BM * LDR];
  __shared__ __align__(16) bf16 Bs[BN * LDR];
  const int tid = threadIdx.x, wave = tid >> 6, lane = tid & 63;
  const int quad = lane >> 4, l16 = lane & 15;
  const int wrow = wave >> 1, wcol = wave & 1;
  const long m0 = (long)blockIdx.y * BM, n0 = (long)blockIdx.x * BN;
  f32x4 acc[MT][NT];
#pragma unroll
  for (int mt = 0; mt < MT; ++mt)
#pragma unroll
    for (int nt = 0; nt < NT; ++nt) acc[mt][nt] = (f32x4){0.f, 0.f, 0.f, 0.f};
  constexpr int ACH = BM * BK / 8 / 256;
  constexpr int BCH = BN * BK / 8 / 256;
  for (int k0 = 0; k0 < K; k0 += BK) {
#pragma unroll
    for (int i = 0; i < ACH; ++i) {
      const int c = i * 256 + tid, r = c >> 2, c4 = c & 3;
      *(bf16x8*)&As[r * LDR + c4 * 8] = *(const bf16x8*)&A[(m0 + r) * K + k0 + c4 * 8];
    }
#pragma unroll
    for (int i = 0; i < BCH; ++i) {
      const int c = i * 256 + tid, r = c >> 2, c4 = c & 3;
      *(bf16x8*)&Bs[r * LDR + c4 * 8] = *(const bf16x8*)&Bt[(n0 + r) * K + k0 + c4 * 8];
    }
    __syncthreads();
    bf16x8 af[MT], bfr[NT];
#pragma unroll
    for (int mt = 0; mt < MT; ++mt)
      af[mt] = *(const bf16x8*)&As[(wrow * MT * 16 + mt * 16 + l16) * LDR + quad * 8];
#pragma unroll
    for (int nt = 0; nt < NT; ++nt)
      bfr[nt] = *(const bf16x8*)&Bs[(wcol * NT * 16 + nt * 16 + l16) * LDR + quad * 8];
#pragma unroll
    for (int mt = 0; mt < MT; ++mt)
#pragma unroll
      for (int nt = 0; nt < NT; ++nt)
        acc[mt][nt] = MFMA16(af[mt], bfr[nt], acc[mt][nt]);
    __syncthreads();
  }
#pragma unroll
  for (int mt = 0; mt < MT; ++mt)
#pragma unroll
    for (int nt = 0; nt < NT; ++nt)
#pragma unroll
      for (int r = 0; r < 4; ++r) {
        const long row = m0 + wrow * MT * 16 + mt * 16 + quad * 4 + r;
        const long col = n0 + wcol * NT * 16 + nt * 16 + l16;
        C[row * (long)N + col] = acc[mt][nt][r];
      }
}

// ---- causal flash attention, 8-wave blocks, 16 q-rows per wave.
// One q-block (128 rows) per block; grid (8 qb) x (128 bh), longest-first.
// Per-wave persistent state ~70 VGPR (qh/ql 16 + o 16 + m/l 8 + staging 12),
// peak ~110 -> fits 128-VGPR budget WITHOUT spills (round-1 failure mode was
// a 64-VGPR cap: second launch_bounds arg is blocks/CU empirically, so (512,2)
// = 2 blocks x 8 waves / 4 SIMD = 4 waves/SIMD = 128-VGPR cap).
// LDS 77824 B -> 2 blocks/CU -> 16 waves/CU regardless.
__global__ __launch_bounds__(512, 2) void k_attn(
    const bf16* __restrict__ Qhi, const bf16* __restrict__ Qlo,
    const bf16* __restrict__ Khi, const bf16* __restrict__ Klo,
    const bf16* __restrict__ Vtg, bf16* __restrict__ Og) {
  __shared__ __align__(16) bf16 KhiS[2 * 64 * 72], KloS[2 * 64 * 72];
  __shared__ __align__(16) bf16 VtS[2 * 64 * 72];
  __shared__ __align__(16) bf16 Ps[8 * 16 * 88];
  const int qb = 7 - blockIdx.x, bh = blockIdx.y;
  const int b = bh >> 4, hh = bh & 15;
  const int tid = threadIdx.x, wave = tid >> 6, lane = tid & 63;
  const int quad = lane >> 4, l16 = lane & 15;
  const long bhS = (long)bh * 1024 * 64;
  const bf16* KhiG = Khi + bhS;
  const bf16* KloG = Klo + bhS;
  const bf16* VtG = Vtg + (long)bh * 64 * 1024;
  const int qbw = qb * 128 + wave * 16;  // this wave's 16-row strip
  bf16* myPs = &Ps[wave * 16 * 88];
  bf16x8 qh[2], ql[2];
  {
    const long rq = (long)(qbw + l16) * 64;
#pragma unroll
    for (int s = 0; s < 2; ++s) {
      qh[s] = *(const bf16x8*)&Qhi[bhS + rq + s * 32 + quad * 8];
      ql[s] = *(const bf16x8*)&Qlo[bhS + rq + s * 32 + quad * 8];
    }
  }
  bf16x8 ones8;
#pragma unroll
  for (int j = 0; j < 8; ++j) ones8[j] = (bf16)1.0f;
  const f32x4 zero4 = {0.f, 0.f, 0.f, 0.f};
  f32x4 o[4];
  float m_i[4], l_i[4];
#pragma unroll
  for (int r = 0; r < 4; ++r) { m_i[r] = -1.0e30f; l_i[r] = 0.f; }
#pragma unroll
  for (int nt = 0; nt < 4; ++nt) o[nt] = zero4;

  // staging: 512 threads cover one 64x64 bf16 chunk per array (1 bf16x8 each)
  const int sr = tid >> 3, sc8 = tid & 7;
  bf16x8 sKh, sKl, sVt;
  auto load_regs = [&](int kc) {
    const int kb = kc * 64;
    sKh = *(const bf16x8*)&KhiG[(long)(kb + sr) * 64 + sc8 * 8];
    sKl = *(const bf16x8*)&KloG[(long)(kb + sr) * 64 + sc8 * 8];
    sVt = *(const bf16x8*)&VtG[(long)sr * 1024 + kb + sc8 * 8];
  };
  auto write_lds = [&](int buf) {
    const int ob = buf * 64 * 72;
    *(bf16x8*)&KhiS[ob + sr * 72 + sc8 * 8] = sKh;
    *(bf16x8*)&KloS[ob + sr * 72 + sc8 * 8] = sKl;
    *(bf16x8*)&VtS[ob + sr * 72 + sc8 * 8] = sVt;
  };
  auto tile_compute = [&](int kb, int buf) {
    const int ob = buf * 64 * 72;
    f32x4 sc[4];
    __builtin_amdgcn_s_setprio(1);
#pragma unroll
    for (int ct = 0; ct < 4; ++ct) {
      const int krow = ob + (ct * 16 + l16) * 72;
      const bf16x8 kh0 = *(const bf16x8*)&KhiS[krow + quad * 8];
      const bf16x8 kh1 = *(const bf16x8*)&KhiS[krow + 32 + quad * 8];
      const bf16x8 kl0 = *(const bf16x8*)&KloS[krow + quad * 8];
      const bf16x8 kl1 = *(const bf16x8*)&KloS[krow + 32 + quad * 8];
      f32x4 s = MFMA16(qh[0], kh0, zero4);
      s = MFMA16(qh[1], kh1, s);
      s = MFMA16(qh[0], kl0, s);
      s = MFMA16(qh[1], kl1, s);
      s = MFMA16(ql[0], kh0, s);
      s = MFMA16(ql[1], kh1, s);
      sc[ct] = s;
    }
    __builtin_amdgcn_s_setprio(0);
    if (kb + 63 > qbw) {
#pragma unroll
      for (int ct = 0; ct < 4; ++ct) {
        const int col = kb + ct * 16 + l16;
#pragma unroll
        for (int r = 0; r < 4; ++r) {
          const int row = qbw + quad * 4 + r;
          if (col > row) sc[ct][r] = -1.0e30f;
        }
      }
    }
    float rmax[4];
#pragma unroll
    for (int r = 0; r < 4; ++r)
      rmax[r] = fmaxf(fmaxf(sc[0][r], sc[1][r]), fmaxf(sc[2][r], sc[3][r]));
#pragma unroll
    for (int off = 1; off < 16; off <<= 1)
#pragma unroll
      for (int r = 0; r < 4; ++r) rmax[r] = fmaxf(rmax[r], __shfl_xor(rmax[r], off));
    float alpha[4];
#pragma unroll
    for (int r = 0; r < 4; ++r) {
      const float mnew = fmaxf(m_i[r], rmax[r]);
      alpha[r] = __builtin_amdgcn_exp2f(m_i[r] - mnew);
      m_i[r] = mnew;
    }
#pragma unroll
    for (int ct = 0; ct < 4; ++ct)
#pragma unroll
      for (int r = 0; r < 4; ++r)
        myPs[(quad * 4 + r) * 88 + ct * 16 + l16] =
            (bf16)__builtin_amdgcn_exp2f(sc[ct][r] - m_i[r]);
    bf16x8 ap[2];
    ap[0] = *(const bf16x8*)&myPs[l16 * 88 + quad * 8];
    ap[1] = *(const bf16x8*)&myPs[l16 * 88 + 32 + quad * 8];
    f32x4 rs = MFMA16(ap[0], ones8, zero4);
    rs = MFMA16(ap[1], ones8, rs);
#pragma unroll
    for (int r = 0; r < 4; ++r) l_i[r] = l_i[r] * alpha[r] + rs[r];
#pragma unroll
    for (int nt = 0; nt < 4; ++nt)
#pragma unroll
      for (int r = 0; r < 4; ++r) o[nt][r] *= alpha[r];
    __builtin_amdgcn_s_setprio(1);
#pragma unroll
    for (int nt = 0; nt < 4; ++nt) {
      const bf16x8 bv0 = *(const bf16x8*)&VtS[ob + (nt * 16 + l16) * 72 + quad * 8];
      const bf16x8 bv1 = *(const bf16x8*)&VtS[ob + (nt * 16 + l16) * 72 + 32 + quad * 8];
      o[nt] = MFMA16(ap[0], bv0, o[nt]);
      o[nt] = MFMA16(ap[1], bv1, o[nt]);
    }
    __builtin_amdgcn_s_setprio(0);
  };

  const int nch = 2 * qb + 2;
  load_regs(0);
  write_lds(0);
  __syncthreads();
  for (int kc = 0; kc < nch; ++kc) {
    const int kb = kc * 64;
    const int buf = kc & 1;
    if (kc + 1 < nch) load_regs(kc + 1);
    if (kb <= qbw + 15) tile_compute(kb, buf);
    if (kc + 1 < nch) write_lds(1 - buf);
    __syncthreads();
  }
  float inv[4];
#pragma unroll
  for (int r = 0; r < 4; ++r) inv[r] = 1.f / l_i[r];
#pragma unroll
  for (int nt = 0; nt < 4; ++nt)
#pragma unroll
    for (int r = 0; r < 4; ++r) {
      const int row = qbw + quad * 4 + r;
      Og[((long)b * 1024 + row) * 1024 + hh * 64 + nt * 16 + l16] =
          (bf16)(o[nt][r] * inv[r]);
    }
}

extern "C" void kernel_launch(void* const* d_in, const int* in_sizes, int n_in,
                              void* d_out, int out_size, void* d_ws, size_t ws_size,
                              hipStream_t stream) {
  const float* x = (const float*)d_in[0];
  const float* cw = (const float*)d_in[1];
  const int* cidx = (const int*)d_in[2];
  const float* wq = (const float*)d_in[3];
  const int* iq = (const int*)d_in[4];
  const float* wk = (const float*)d_in[5];
  const int* ik = (const int*)d_in[6];
  const float* wv = (const float*)d_in[7];
  const int* iv = (const int*)d_in[8];
  const float* neurons = (const float*)d_in[9];
  const float* pool = (const float*)d_in[10];
  const float* WO = (const float*)d_in[11];
  float* out = (float*)d_out;
  char* ws = (char*)d_ws;
  // Workspace (86 MB peak, lifetime-overlapped):
  //   [ 0,16) Khi | [16,32) Klo | [32,48) Vt (all bf16)
  //   [48,64) att bf16 -- prep overlay: Wc f32 [48,52), Wn f32 [52,64)
  //   [64,66) WcTh | [66,68) WcTl   bf16 [8][128][1024]
  //   [68,74) Wth  | [74,80) Wtl    bf16 [24][1024][128]
  //   [80,82) hh   | [82,84) hl     bf16 [8][1024][128]
  //   [84,86) WOb bf16
  //   Qhi/Qlo bf16 in d_out (2 x 16 MB), dead before the final f32 write.
  bf16* Khi = (bf16*)(ws + (0l << 20));
  bf16* Klo = (bf16*)(ws + (16l << 20));
  bf16* Vt = (bf16*)(ws + (32l << 20));
  bf16* att = (bf16*)(ws + (48l << 20));
  float* Wc = (float*)(ws + (48l << 20));
  float* Wn = (float*)(ws + (52l << 20));
  bf16* WcTh = (bf16*)(ws + (64l << 20));
  bf16* WcTl = (bf16*)(ws + (66l << 20));
  bf16* Wth = (bf16*)(ws + (68l << 20));
  bf16* Wtl = (bf16*)(ws + (74l << 20));
  bf16* hh = (bf16*)(ws + (80l << 20));
  bf16* hl = (bf16*)(ws + (82l << 20));
  bf16* WOb = (bf16*)(ws + (84l << 20));
  bf16* Qhi = (bf16*)d_out;
  bf16* Qlo = (bf16*)d_out + (8l << 20);

  k_cvt<<<1024, 256, 0, stream>>>(WO, WOb, 1024l * 1024);
  k_build_wc<<<dim3(1024, 8), 128, 0, stream>>>(neurons, cw, cidx, Wc);
  k_build_mix<<<dim3(4, 128, 24), 256, 0, stream>>>(pool, wq, iq, wk, ik, wv, iv, Wn);
  k_transpose_split<<<dim3(2, 16, 8), 256, 0, stream>>>(Wc, WcTh, WcTl, 1024, 128);
  k_transpose_split<<<dim3(16, 2, 24), 256, 0, stream>>>(Wn, Wth, Wtl, 128, 1024);
  // h = x * Wc (split A in-kernel, dual B), out split-pair hh/hl [8][1024][128]
  k_gemm_h<<<dim3(2, 16, 8), 256, 0, stream>>>(
      x, WcTh, WcTl, hh, hl, 1024, 128, 1024, 1l << 20, 1l << 17, 1l << 17);
  // Q = (h*Wq) * (log2e/8), split-pair out, head-split
  k_gemm_dual<true><<<dim3(16, 16, 8), 256, 0, stream>>>(
      hh, hl, Wth, Wtl, Qhi, Qlo, 1024, 1024, 128, 1l << 17, 1l << 17, 1l << 20,
      1, 2, 0.125f * 1.44269504088896f);
  // K split-pair out, head-split
  k_gemm_dual<true><<<dim3(16, 16, 8), 256, 0, stream>>>(
      hh, hl, Wth + (8l << 17), Wtl + (8l << 17), Khi, Klo, 1024, 1024, 128,
      1l << 17, 1l << 17, 1l << 20, 1, 2, 1.f);
  // V^T: A=Wt_V (hi only), B=h (hi only), plain bf16 out [b][d][s]
  k_gemm_dual<false><<<dim3(16, 16, 8), 256, 0, stream>>>(
      Wth + (16l << 17), nullptr, hh, nullptr, Vt, nullptr, 1024, 1024, 128,
      1l << 17, 1l << 17, 1l << 20, 0, 0, 1.f);
  k_attn<<<dim3(8, 128), 512, 0, stream>>>(Qhi, Qlo, Khi, Klo, Vt, att);
  // out(f32, 8192x1024) = att * W_O^T
  k_gemm_bt<128, 128><<<dim3(8, 64, 1), 256, 0, stream>>>(att, WOb, out, 8192, 1024, 1024);
}

// Round 4
// 368.609 us; speedup vs baseline: 1.0961x; 1.0313x over previous
//
#include <hip/hip_runtime.h>

typedef __bf16 bf16;
typedef __bf16 bf16x4 __attribute__((ext_vector_type(4)));
typedef __bf16 bf16x8 __attribute__((ext_vector_type(8)));
typedef float f32x4 __attribute__((ext_vector_type(4)));

__device__ __forceinline__ f32x4 MFMA16(bf16x8 a, bf16x8 b, f32x4 c) {
  return __builtin_amdgcn_mfma_f32_16x16x32_bf16(a, b, c, 0, 0, 0);
}

__device__ __forceinline__ bf16 split_hi(float v) { return (bf16)v; }
__device__ __forceinline__ bf16 split_lo(float v) { return (bf16)(v - (float)(bf16)v); }

// ---- f32 -> bf16 bulk convert ----
__global__ void k_cvt(const float* __restrict__ in, bf16* __restrict__ out, long n) {
  const long i = ((long)blockIdx.x * 256 + threadIdx.x) * 4;
  if (i < n) {
    const f32x4 v = *(const f32x4*)&in[i];
    bf16x4 o;
#pragma unroll
    for (int j = 0; j < 4; ++j) o[j] = (bf16)v[j];
    *(bf16x4*)&out[i] = o;
  }
}

// ---- Wc[b][d][r] = sum_k w[b,k] * neurons[idx[b,k]][d][r]  (f32 out) ----
__global__ void k_build_wc(const float* __restrict__ neurons, const float* __restrict__ w,
                           const int* __restrict__ idx, float* __restrict__ Wc) {
  const int d = blockIdx.x, b = blockIdx.y, r = threadIdx.x;
  float acc = 0.f;
#pragma unroll
  for (int k = 0; k < 16; ++k) {
    const float wk = w[b * 16 + k];
    const int ni = idx[b * 16 + k];
    acc += wk * neurons[((long)ni * 1024 + d) * 128 + r];
  }
  Wc[((long)b * 1024 + d) * 128 + r] = acc;
}

// ---- Wn[z=which*8+b][r][d] = sum_k w[b,k] * pool[idx[b,k]][r][d]  (f32 out) ----
__global__ void k_build_mix(const float* __restrict__ pool,
                            const float* __restrict__ wq, const int* __restrict__ iq,
                            const float* __restrict__ wk, const int* __restrict__ ik,
                            const float* __restrict__ wv, const int* __restrict__ iv,
                            float* __restrict__ Wn) {
  const int d = blockIdx.x * 256 + threadIdx.x;
  const int r = blockIdx.y;
  const int z = blockIdx.z, which = z >> 3, b = z & 7;
  const float* wp = which == 0 ? wq : (which == 1 ? wk : wv);
  const int* ip = which == 0 ? iq : (which == 1 ? ik : iv);
  float acc = 0.f;
#pragma unroll
  for (int k = 0; k < 8; ++k) {
    const float wkk = wp[b * 8 + k];
    const int ni = ip[b * 8 + k];
    acc += wkk * pool[((long)ni * 128 + r) * 1024 + d];
  }
  Wn[((long)z * 128 + r) * 1024 + d] = acc;
}

// ---- batched transpose f32 [M][N] -> split bf16 pair [N][M] ----
__global__ void k_transpose_split(const float* __restrict__ in, bf16* __restrict__ outh,
                                  bf16* __restrict__ outl, int M, int N) {
  __shared__ float t[64][65];
  const int n0 = blockIdx.x * 64, m0 = blockIdx.y * 64;
  const long base = (long)blockIdx.z * M * N;
  const int tid = threadIdx.x;
#pragma unroll
  for (int i = 0; i < 16; ++i) {
    const int lin = i * 256 + tid;
    const int r = lin >> 6, c = lin & 63;
    t[r][c] = in[base + (long)(m0 + r) * N + (n0 + c)];
  }
  __syncthreads();
#pragma unroll
  for (int i = 0; i < 16; ++i) {
    const int lin = i * 256 + tid;
    const int r = lin >> 6, c = lin & 63;
    const float v = t[c][r];
    const long off = base + (long)(n0 + r) * M + (m0 + c);
    outh[off] = split_hi(v);
    outl[off] = split_lo(v);
  }
}

// ---- h-GEMM: A f32 (split in-kernel), Bt pre-split bf16 pair; out split-pair.
// A [M][K] f32, Bt[n][k] pair. M=1024 N=128 K=1024. BM=BN=64, 4 waves 2x2.
__global__ __launch_bounds__(256) void k_gemm_h(
    const float* __restrict__ A, const bf16* __restrict__ Bth,
    const bf16* __restrict__ Btl, bf16* __restrict__ Ch, bf16* __restrict__ Cl,
    int M, int N, int K, long sA, long sB, long sC) {
  constexpr int LDR = 40;
  __shared__ __align__(16) bf16 Ash[64 * LDR], Asl[64 * LDR];
  __shared__ __align__(16) bf16 Bsh[64 * LDR], Bsl[64 * LDR];
  const int tid = threadIdx.x, wave = tid >> 6, lane = tid & 63;
  const int quad = lane >> 4, l16 = lane & 15;
  const int wrow = wave >> 1, wcol = wave & 1;
  const int z = blockIdx.z;
  const float* Ap = A + (long)z * sA;
  const bf16* Bph = Bth + (long)z * sB;
  const bf16* Bpl = Btl + (long)z * sB;
  const long m0 = (long)blockIdx.y * 64, n0 = (long)blockIdx.x * 64;
  f32x4 acc[2][2];
#pragma unroll
  for (int mt = 0; mt < 2; ++mt)
#pragma unroll
    for (int nt = 0; nt < 2; ++nt) acc[mt][nt] = (f32x4){0.f, 0.f, 0.f, 0.f};
  for (int k0 = 0; k0 < K; k0 += 32) {
#pragma unroll
    for (int i = 0; i < 2; ++i) {
      const int c = i * 256 + tid, r = c >> 3, c4 = c & 7;
      const f32x4 v = *(const f32x4*)&Ap[(m0 + r) * K + k0 + c4 * 4];
      bf16x4 h4, l4;
#pragma unroll
      for (int j = 0; j < 4; ++j) { h4[j] = split_hi(v[j]); l4[j] = split_lo(v[j]); }
      *(bf16x4*)&Ash[r * LDR + c4 * 4] = h4;
      *(bf16x4*)&Asl[r * LDR + c4 * 4] = l4;
    }
    {
      const int r = tid >> 2, c8 = tid & 3;
      *(bf16x8*)&Bsh[r * LDR + c8 * 8] = *(const bf16x8*)&Bph[(n0 + r) * K + k0 + c8 * 8];
      *(bf16x8*)&Bsl[r * LDR + c8 * 8] = *(const bf16x8*)&Bpl[(n0 + r) * K + k0 + c8 * 8];
    }
    __syncthreads();
    bf16x8 ah[2], al[2], bh[2], bl[2];
#pragma unroll
    for (int mt = 0; mt < 2; ++mt) {
      const int row = wrow * 32 + mt * 16 + l16;
      ah[mt] = *(const bf16x8*)&Ash[row * LDR + quad * 8];
      al[mt] = *(const bf16x8*)&Asl[row * LDR + quad * 8];
    }
#pragma unroll
    for (int nt = 0; nt < 2; ++nt) {
      const int row = wcol * 32 + nt * 16 + l16;
      bh[nt] = *(const bf16x8*)&Bsh[row * LDR + quad * 8];
      bl[nt] = *(const bf16x8*)&Bsl[row * LDR + quad * 8];
    }
#pragma unroll
    for (int mt = 0; mt < 2; ++mt)
#pragma unroll
      for (int nt = 0; nt < 2; ++nt) {
        acc[mt][nt] = MFMA16(ah[mt], bh[nt], acc[mt][nt]);
        acc[mt][nt] = MFMA16(ah[mt], bl[nt], acc[mt][nt]);
        acc[mt][nt] = MFMA16(al[mt], bh[nt], acc[mt][nt]);
      }
    __syncthreads();
  }
#pragma unroll
  for (int mt = 0; mt < 2; ++mt)
#pragma unroll
    for (int nt = 0; nt < 2; ++nt)
#pragma unroll
      for (int r = 0; r < 4; ++r) {
        const long row = m0 + wrow * 32 + mt * 16 + quad * 4 + r;
        const long col = n0 + wcol * 32 + nt * 16 + l16;
        const float v = acc[mt][nt][r];
        const long off = (long)z * sC + row * (long)N + col;
        const bf16 hi = (bf16)v;
        Ch[off] = hi;
        Cl[off] = (bf16)(v - (float)hi);
      }
}

// ---- dual-bf16 GEMM: A pair [M][K], Bt pair [N][K] (both pre-split).
// SPLIT: 3 MFMAs (hh+hl+lh); else hi-only, 1 MFMA.
// mode: 0 = bf16 out, 2 = split-pair out. split_heads: C[(col/64)][row][col%64].
template <bool SPLIT>
__global__ __launch_bounds__(256) void k_gemm_dual(
    const bf16* __restrict__ Ah, const bf16* __restrict__ Al,
    const bf16* __restrict__ Bth, const bf16* __restrict__ Btl,
    bf16* __restrict__ C, bf16* __restrict__ C2, int M, int N, int K,
    long sA, long sB, long sC, int split_heads, int mode, float scale) {
  constexpr int LDR = 40;
  __shared__ __align__(16) bf16 Ash[64 * LDR], Bsh[64 * LDR];
  __shared__ __align__(16) bf16 Asl[SPLIT ? 64 * LDR : 1];
  __shared__ __align__(16) bf16 Bsl[SPLIT ? 64 * LDR : 1];
  const int tid = threadIdx.x, wave = tid >> 6, lane = tid & 63;
  const int quad = lane >> 4, l16 = lane & 15;
  const int wrow = wave >> 1, wcol = wave & 1;
  const int z = blockIdx.z;
  const bf16* Aph = Ah + (long)z * sA;
  const bf16* Apl = Al + (long)z * sA;
  const bf16* Bph = Bth + (long)z * sB;
  const bf16* Bpl = Btl + (long)z * sB;
  const long m0 = (long)blockIdx.y * 64, n0 = (long)blockIdx.x * 64;
  f32x4 acc[2][2];
#pragma unroll
  for (int mt = 0; mt < 2; ++mt)
#pragma unroll
    for (int nt = 0; nt < 2; ++nt) acc[mt][nt] = (f32x4){0.f, 0.f, 0.f, 0.f};
  for (int k0 = 0; k0 < K; k0 += 32) {
    {
      const int r = tid >> 2, c8 = tid & 3;
      *(bf16x8*)&Ash[r * LDR + c8 * 8] = *(const bf16x8*)&Aph[(m0 + r) * K + k0 + c8 * 8];
      if (SPLIT)
        *(bf16x8*)&Asl[r * LDR + c8 * 8] = *(const bf16x8*)&Apl[(m0 + r) * K + k0 + c8 * 8];
      *(bf16x8*)&Bsh[r * LDR + c8 * 8] = *(const bf16x8*)&Bph[(n0 + r) * K + k0 + c8 * 8];
      if (SPLIT)
        *(bf16x8*)&Bsl[r * LDR + c8 * 8] = *(const bf16x8*)&Bpl[(n0 + r) * K + k0 + c8 * 8];
    }
    __syncthreads();
    bf16x8 ah[2], al[2], bh[2], bl[2];
#pragma unroll
    for (int mt = 0; mt < 2; ++mt) {
      const int row = wrow * 32 + mt * 16 + l16;
      ah[mt] = *(const bf16x8*)&Ash[row * LDR + quad * 8];
      if (SPLIT) al[mt] = *(const bf16x8*)&Asl[row * LDR + quad * 8];
    }
#pragma unroll
    for (int nt = 0; nt < 2; ++nt) {
      const int row = wcol * 32 + nt * 16 + l16;
      bh[nt] = *(const bf16x8*)&Bsh[row * LDR + quad * 8];
      if (SPLIT) bl[nt] = *(const bf16x8*)&Bsl[row * LDR + quad * 8];
    }
#pragma unroll
    for (int mt = 0; mt < 2; ++mt)
#pragma unroll
      for (int nt = 0; nt < 2; ++nt) {
        acc[mt][nt] = MFMA16(ah[mt], bh[nt], acc[mt][nt]);
        if (SPLIT) {
          acc[mt][nt] = MFMA16(ah[mt], bl[nt], acc[mt][nt]);
          acc[mt][nt] = MFMA16(al[mt], bh[nt], acc[mt][nt]);
        }
      }
    __syncthreads();
  }
#pragma unroll
  for (int mt = 0; mt < 2; ++mt)
#pragma unroll
    for (int nt = 0; nt < 2; ++nt)
#pragma unroll
      for (int r = 0; r < 4; ++r) {
        const long row = m0 + wrow * 32 + mt * 16 + quad * 4 + r;
        const long col = n0 + wcol * 32 + nt * 16 + l16;
        const float v = acc[mt][nt][r] * scale;
        const long off = (long)z * sC +
                         (split_heads ? ((col >> 6) * ((long)M * 64) + row * 64 + (col & 63))
                                      : (row * (long)N + col));
        if (mode == 2) {
          const bf16 hi = (bf16)v;
          C[off] = hi;
          C2[off] = (bf16)(v - (float)hi);
        } else {
          C[off] = (bf16)v;
        }
      }
}

// ---- plain bf16 GEMM (output projection): C = A(MxK) * Bt[n][k], out f32. ----
template <int BM, int BN>
__global__ __launch_bounds__(256) void k_gemm_bt(
    const bf16* __restrict__ A, const bf16* __restrict__ Bt, float* __restrict__ C,
    int M, int N, int K) {
  constexpr int BK = 32, LDR = BK + 8;
  constexpr int MT = BM / 32, NT = BN / 32;
  __shared__ __align__(16) bf16 As[BM * LDR];
  __shared__ __align__(16) bf16 Bs[BN * LDR];
  const int tid = threadIdx.x, wave = tid >> 6, lane = tid & 63;
  const int quad = lane >> 4, l16 = lane & 15;
  const int wrow = wave >> 1, wcol = wave & 1;
  const long m0 = (long)blockIdx.y * BM, n0 = (long)blockIdx.x * BN;
  f32x4 acc[MT][NT];
#pragma unroll
  for (int mt = 0; mt < MT; ++mt)
#pragma unroll
    for (int nt = 0; nt < NT; ++nt) acc[mt][nt] = (f32x4){0.f, 0.f, 0.f, 0.f};
  constexpr int ACH = BM * BK / 8 / 256;
  constexpr int BCH = BN * BK / 8 / 256;
  for (int k0 = 0; k0 < K; k0 += BK) {
#pragma unroll
    for (int i = 0; i < ACH; ++i) {
      const int c = i * 256 + tid, r = c >> 2, c4 = c & 3;
      *(bf16x8*)&As[r * LDR + c4 * 8] = *(const bf16x8*)&A[(m0 + r) * K + k0 + c4 * 8];
    }
#pragma unroll
    for (int i = 0; i < BCH; ++i) {
      const int c = i * 256 + tid, r = c >> 2, c4 = c & 3;
      *(bf16x8*)&Bs[r * LDR + c4 * 8] = *(const bf16x8*)&Bt[(n0 + r) * K + k0 + c4 * 8];
    }
    __syncthreads();
    bf16x8 af[MT], bfr[NT];
#pragma unroll
    for (int mt = 0; mt < MT; ++mt)
      af[mt] = *(const bf16x8*)&As[(wrow * MT * 16 + mt * 16 + l16) * LDR + quad * 8];
#pragma unroll
    for (int nt = 0; nt < NT; ++nt)
      bfr[nt] = *(const bf16x8*)&Bs[(wcol * NT * 16 + nt * 16 + l16) * LDR + quad * 8];
#pragma unroll
    for (int mt = 0; mt < MT; ++mt)
#pragma unroll
      for (int nt = 0; nt < NT; ++nt)
        acc[mt][nt] = MFMA16(af[mt], bfr[nt], acc[mt][nt]);
    __syncthreads();
  }
#pragma unroll
  for (int mt = 0; mt < MT; ++mt)
#pragma unroll
    for (int nt = 0; nt < NT; ++nt)
#pragma unroll
      for (int r = 0; r < 4; ++r) {
        const long row = m0 + wrow * MT * 16 + mt * 16 + quad * 4 + r;
        const long col = n0 + wcol * NT * 16 + nt * 16 + l16;
        C[row * (long)N + col] = acc[mt][nt][r];
      }
}

// ---- causal flash attention v4: swapped QK^T (S^T = K x Q^T) + in-register
// softmax; NO P LDS roundtrip. 1024-thread blocks, 16 waves: waves 0-7 ->
// q-block p (16 rows each), waves 8-15 -> q-block 7-p. Compute per block =
// (2p+2)+(16-2p) = 18 wave-chunks for every p -> balanced; K/V staging shared
// between the paired tiles (restores round-0's 96 MB fetch).
// K is stored in LDS with a permuted row order so the swapped-QK output lands
// per-lane exactly in PV's B-fragment order: stored row i holds true k-row
//   k(i) = (i>>5)*32 + ((i>>2)&3)*8 + ((i>>4)&1)*4 + (i&3)
// (i.e. lane(quad) accumulates k = s*32+quad*8+j across the 4 ct-tiles).
// Softmax: per-lane over 16 regs + 2 shfl_xor (m,l are per-lane scalars).
// P -> bf16 is 32 plain casts; PV is o^T = V^T x P^T with V frags read from
// the same VtS addresses as before. Output packed bf16x4 per nt.
__global__ __launch_bounds__(1024, 1) void k_attn(
    const bf16* __restrict__ Qhi, const bf16* __restrict__ Qlo,
    const bf16* __restrict__ Khi, const bf16* __restrict__ Klo,
    const bf16* __restrict__ Vtg, bf16* __restrict__ Og) {
  __shared__ __align__(16) bf16 KhiS[2 * 64 * 72], KloS[2 * 64 * 72];
  __shared__ __align__(16) bf16 VtS[2 * 64 * 72];
  const int p = blockIdx.x, bh = blockIdx.y;
  const int b = bh >> 4, hh = bh & 15;
  const int tid = threadIdx.x, wave = tid >> 6, lane = tid & 63;
  const int quad = lane >> 4, l16 = lane & 15;
  const long bhS = (long)bh * 1024 * 64;
  const bf16* KhiG = Khi + bhS;
  const bf16* KloG = Klo + bhS;
  const bf16* VtG = Vtg + (long)bh * 64 * 1024;
  const int qb = (wave < 8) ? p : (7 - p);
  const int qbw = qb * 128 + (wave & 7) * 16;  // this wave's 16-row strip
  bf16x8 qh[2], ql[2];
  {
    const long rq = (long)(qbw + l16) * 64;
#pragma unroll
    for (int s = 0; s < 2; ++s) {
      qh[s] = *(const bf16x8*)&Qhi[bhS + rq + s * 32 + quad * 8];
      ql[s] = *(const bf16x8*)&Qlo[bhS + rq + s * 32 + quad * 8];
    }
  }
  const f32x4 zero4 = {0.f, 0.f, 0.f, 0.f};
  f32x4 o[4];
  float m_i = -1.0e30f, l_i = 0.f;
#pragma unroll
  for (int nt = 0; nt < 4; ++nt) o[nt] = zero4;

  // staging: waves 0-7 (512 thr) load K hi+lo; waves 8-15 load Vt.
  const int st = tid & 511;
  const int sr = st >> 3, sc8 = st & 7;
  const bool isK = tid < 512;
  // permuted K store row (inverse of k(i) above): i = 32*(sr>>5) +
  // 16*((sr>>2)&1) + 4*((sr>>3)&3) + (sr&3)
  const int pr = ((sr >> 5) * 2 + ((sr >> 2) & 1)) * 16 + ((sr >> 3) & 3) * 4 + (sr & 3);
  bf16x8 sA, sB;
  auto load_regs = [&](int kc) {
    const int kb = kc * 64;
    if (isK) {
      sA = *(const bf16x8*)&KhiG[(long)(kb + sr) * 64 + sc8 * 8];
      sB = *(const bf16x8*)&KloG[(long)(kb + sr) * 64 + sc8 * 8];
    } else {
      sA = *(const bf16x8*)&VtG[(long)sr * 1024 + kb + sc8 * 8];
    }
  };
  auto write_lds = [&](int buf) {
    const int ob = buf * 64 * 72;
    if (isK) {
      *(bf16x8*)&KhiS[ob + pr * 72 + sc8 * 8] = sA;
      *(bf16x8*)&KloS[ob + pr * 72 + sc8 * 8] = sB;
    } else {
      *(bf16x8*)&VtS[ob + sr * 72 + sc8 * 8] = sA;
    }
  };
  auto tile_compute = [&](int kb, int buf) {
    const int ob = buf * 64 * 72;
    f32x4 sc[4];
    __builtin_amdgcn_s_setprio(1);
#pragma unroll
    for (int ct = 0; ct < 4; ++ct) {
      const int krow = ob + (ct * 16 + l16) * 72;
      const bf16x8 kh0 = *(const bf16x8*)&KhiS[krow + quad * 8];
      const bf16x8 kh1 = *(const bf16x8*)&KhiS[krow + 32 + quad * 8];
      const bf16x8 kl0 = *(const bf16x8*)&KloS[krow + quad * 8];
      const bf16x8 kl1 = *(const bf16x8*)&KloS[krow + 32 + quad * 8];
      f32x4 s = MFMA16(kh0, qh[0], zero4);
      s = MFMA16(kh1, qh[1], s);
      s = MFMA16(kl0, qh[0], s);
      s = MFMA16(kl1, qh[1], s);
      s = MFMA16(kh0, ql[0], s);
      s = MFMA16(kh1, ql[1], s);
      sc[ct] = s;
    }
    __builtin_amdgcn_s_setprio(0);
    // lane holds S^T[k][q=qbw+l16]; true k = kb + (ct>>1)*32 + quad*8 + (ct&1)*4 + r
    const int q_glob = qbw + l16;
    if (kb + 63 > qbw) {
#pragma unroll
      for (int ct = 0; ct < 4; ++ct) {
        const int kbase = kb + (ct >> 1) * 32 + quad * 8 + (ct & 1) * 4;
#pragma unroll
        for (int r = 0; r < 4; ++r)
          if (kbase + r > q_glob) sc[ct][r] = -1.0e30f;
      }
    }
    float mx = sc[0][0];
#pragma unroll
    for (int ct = 0; ct < 4; ++ct)
#pragma unroll
      for (int r = 0; r < 4; ++r) mx = fmaxf(mx, sc[ct][r]);
    mx = fmaxf(mx, __shfl_xor(mx, 16));
    mx = fmaxf(mx, __shfl_xor(mx, 32));
    const float mnew = fmaxf(m_i, mx);
    const float alpha = __builtin_amdgcn_exp2f(m_i - mnew);
    m_i = mnew;
    float psum = 0.f;
#pragma unroll
    for (int ct = 0; ct < 4; ++ct)
#pragma unroll
      for (int r = 0; r < 4; ++r) {
        const float pv = __builtin_amdgcn_exp2f(sc[ct][r] - mnew);
        sc[ct][r] = pv;
        psum += pv;
      }
    psum += __shfl_xor(psum, 16);
    psum += __shfl_xor(psum, 32);
    l_i = l_i * alpha + psum;
#pragma unroll
    for (int nt = 0; nt < 4; ++nt)
#pragma unroll
      for (int r = 0; r < 4; ++r) o[nt][r] *= alpha;
    // pack P^T b-frags: pb[s][c*4+r] = P[q=l16][k = s*32+quad*8+c*4+r]
    bf16x8 pb0, pb1;
#pragma unroll
    for (int c = 0; c < 2; ++c)
#pragma unroll
      for (int r = 0; r < 4; ++r) {
        pb0[c * 4 + r] = (bf16)sc[c][r];
        pb1[c * 4 + r] = (bf16)sc[2 + c][r];
      }
    __builtin_amdgcn_s_setprio(1);
#pragma unroll
    for (int nt = 0; nt < 4; ++nt) {
      const bf16x8 bv0 = *(const bf16x8*)&VtS[ob + (nt * 16 + l16) * 72 + quad * 8];
      const bf16x8 bv1 = *(const bf16x8*)&VtS[ob + (nt * 16 + l16) * 72 + 32 + quad * 8];
      o[nt] = MFMA16(bv0, pb0, o[nt]);
      o[nt] = MFMA16(bv1, pb1, o[nt]);
    }
    __builtin_amdgcn_s_setprio(0);
  };

  const int nch = 2 * (7 - p) + 2;
  load_regs(0);
  write_lds(0);
  __syncthreads();
  for (int kc = 0; kc < nch; ++kc) {
    const int kb = kc * 64;
    const int buf = kc & 1;
    if (kc + 1 < nch) load_regs(kc + 1);
    if (kb <= qbw + 15) tile_compute(kb, buf);
    if (kc + 1 < nch) write_lds(1 - buf);
    __syncthreads();
  }
  // lane holds o^T[d = nt*16+quad*4+r][q = qbw+l16]
  const float inv = 1.f / l_i;
  const long orow = ((long)b * 1024 + qbw + l16) * 1024 + hh * 64;
#pragma unroll
  for (int nt = 0; nt < 4; ++nt) {
    bf16x4 v4;
#pragma unroll
    for (int r = 0; r < 4; ++r) v4[r] = (bf16)(o[nt][r] * inv);
    *(bf16x4*)&Og[orow + nt * 16 + quad * 4] = v4;
  }
}

extern "C" void kernel_launch(void* const* d_in, const int* in_sizes, int n_in,
                              void* d_out, int out_size, void* d_ws, size_t ws_size,
                              hipStream_t stream) {
  const float* x = (const float*)d_in[0];
  const float* cw = (const float*)d_in[1];
  const int* cidx = (const int*)d_in[2];
  const float* wq = (const float*)d_in[3];
  const int* iq = (const int*)d_in[4];
  const float* wk = (const float*)d_in[5];
  const int* ik = (const int*)d_in[6];
  const float* wv = (const float*)d_in[7];
  const int* iv = (const int*)d_in[8];
  const float* neurons = (const float*)d_in[9];
  const float* pool = (const float*)d_in[10];
  const float* WO = (const float*)d_in[11];
  float* out = (float*)d_out;
  char* ws = (char*)d_ws;
  // Workspace (86 MB peak, lifetime-overlapped):
  //   [ 0,16) Khi | [16,32) Klo | [32,48) Vt (all bf16)
  //   [48,64) att bf16 -- prep overlay: Wc f32 [48,52), Wn f32 [52,64)
  //   [64,66) WcTh | [66,68) WcTl   bf16 [8][128][1024]
  //   [68,74) Wth  | [74,80) Wtl    bf16 [24][1024][128]
  //   [80,82) hh   | [82,84) hl     bf16 [8][1024][128]
  //   [84,86) WOb bf16
  //   Qhi/Qlo bf16 in d_out (2 x 16 MB), dead before the final f32 write.
  bf16* Khi = (bf16*)(ws + (0l << 20));
  bf16* Klo = (bf16*)(ws + (16l << 20));
  bf16* Vt = (bf16*)(ws + (32l << 20));
  bf16* att = (bf16*)(ws + (48l << 20));
  float* Wc = (float*)(ws + (48l << 20));
  float* Wn = (float*)(ws + (52l << 20));
  bf16* WcTh = (bf16*)(ws + (64l << 20));
  bf16* WcTl = (bf16*)(ws + (66l << 20));
  bf16* Wth = (bf16*)(ws + (68l << 20));
  bf16* Wtl = (bf16*)(ws + (74l << 20));
  bf16* hh = (bf16*)(ws + (80l << 20));
  bf16* hl = (bf16*)(ws + (82l << 20));
  bf16* WOb = (bf16*)(ws + (84l << 20));
  bf16* Qhi = (bf16*)d_out;
  bf16* Qlo = (bf16*)d_out + (8l << 20);

  k_cvt<<<1024, 256, 0, stream>>>(WO, WOb, 1024l * 1024);
  k_build_wc<<<dim3(1024, 8), 128, 0, stream>>>(neurons, cw, cidx, Wc);
  k_build_mix<<<dim3(4, 128, 24), 256, 0, stream>>>(pool, wq, iq, wk, ik, wv, iv, Wn);
  k_transpose_split<<<dim3(2, 16, 8), 256, 0, stream>>>(Wc, WcTh, WcTl, 1024, 128);
  k_transpose_split<<<dim3(16, 2, 24), 256, 0, stream>>>(Wn, Wth, Wtl, 128, 1024);
  // h = x * Wc (split A in-kernel, dual B), out split-pair hh/hl [8][1024][128]
  k_gemm_h<<<dim3(2, 16, 8), 256, 0, stream>>>(
      x, WcTh, WcTl, hh, hl, 1024, 128, 1024, 1l << 20, 1l << 17, 1l << 17);
  // Q = (h*Wq) * (log2e/8), split-pair out, head-split
  k_gemm_dual<true><<<dim3(16, 16, 8), 256, 0, stream>>>(
      hh, hl, Wth, Wtl, Qhi, Qlo, 1024, 1024, 128, 1l << 17, 1l << 17, 1l << 20,
      1, 2, 0.125f * 1.44269504088896f);
  // K split-pair out, head-split
  k_gemm_dual<true><<<dim3(16, 16, 8), 256, 0, stream>>>(
      hh, hl, Wth + (8l << 17), Wtl + (8l << 17), Khi, Klo, 1024, 1024, 128,
      1l << 17, 1l << 17, 1l << 20, 1, 2, 1.f);
  // V^T: A=Wt_V (hi only), B=h (hi only), plain bf16 out [b][d][s]
  k_gemm_dual<false><<<dim3(16, 16, 8), 256, 0, stream>>>(
      Wth + (16l << 17), nullptr, hh, nullptr, Vt, nullptr, 1024, 1024, 128,
      1l << 17, 1l << 17, 1l << 20, 0, 0, 1.f);
  k_attn<<<dim3(4, 128), 1024, 0, stream>>>(Qhi, Qlo, Khi, Klo, Vt, att);
  // out(f32, 8192x1024) = att * W_O^T
  k_gemm_bt<128, 128><<<dim3(8, 64, 1), 256, 0, stream>>>(att, WOb, out, 8192, 1024, 1024);
}

// Round 5
// 342.532 us; speedup vs baseline: 1.1796x; 1.0761x over previous
//
#include <hip/hip_runtime.h>

typedef __bf16 bf16;
typedef __bf16 bf16x4 __attribute__((ext_vector_type(4)));
typedef __bf16 bf16x8 __attribute__((ext_vector_type(8)));
typedef float f32x4 __attribute__((ext_vector_type(4)));

__device__ __forceinline__ f32x4 MFMA16(bf16x8 a, bf16x8 b, f32x4 c) {
  return __builtin_amdgcn_mfma_f32_16x16x32_bf16(a, b, c, 0, 0, 0);
}

__device__ __forceinline__ bf16 split_hi(float v) { return (bf16)v; }
__device__ __forceinline__ bf16 split_lo(float v) { return (bf16)(v - (float)(bf16)v); }

// ---- f32 -> bf16 bulk convert ----
__global__ void k_cvt(const float* __restrict__ in, bf16* __restrict__ out, long n) {
  const long i = ((long)blockIdx.x * 256 + threadIdx.x) * 4;
  if (i < n) {
    const f32x4 v = *(const f32x4*)&in[i];
    bf16x4 o;
#pragma unroll
    for (int j = 0; j < 4; ++j) o[j] = (bf16)v[j];
    *(bf16x4*)&out[i] = o;
  }
}

// ---- Wc[b][d][r] = sum_k w[b,k] * neurons[idx[b,k]][d][r]  (f32 out) ----
__global__ void k_build_wc(const float* __restrict__ neurons, const float* __restrict__ w,
                           const int* __restrict__ idx, float* __restrict__ Wc) {
  const int d = blockIdx.x, b = blockIdx.y, r = threadIdx.x;
  float acc = 0.f;
#pragma unroll
  for (int k = 0; k < 16; ++k) {
    const float wk = w[b * 16 + k];
    const int ni = idx[b * 16 + k];
    acc += wk * neurons[((long)ni * 1024 + d) * 128 + r];
  }
  Wc[((long)b * 1024 + d) * 128 + r] = acc;
}

// ---- Wn[z=which*8+b][r][d] = sum_k w[b,k] * pool[idx[b,k]][r][d]  (f32 out) ----
__global__ void k_build_mix(const float* __restrict__ pool,
                            const float* __restrict__ wq, const int* __restrict__ iq,
                            const float* __restrict__ wk, const int* __restrict__ ik,
                            const float* __restrict__ wv, const int* __restrict__ iv,
                            float* __restrict__ Wn) {
  const int d = blockIdx.x * 256 + threadIdx.x;
  const int r = blockIdx.y;
  const int z = blockIdx.z, which = z >> 3, b = z & 7;
  const float* wp = which == 0 ? wq : (which == 1 ? wk : wv);
  const int* ip = which == 0 ? iq : (which == 1 ? ik : iv);
  float acc = 0.f;
#pragma unroll
  for (int k = 0; k < 8; ++k) {
    const float wkk = wp[b * 8 + k];
    const int ni = ip[b * 8 + k];
    acc += wkk * pool[((long)ni * 128 + r) * 1024 + d];
  }
  Wn[((long)z * 128 + r) * 1024 + d] = acc;
}

// ---- batched transpose f32 [M][N] -> split bf16 pair [N][M] ----
__global__ void k_transpose_split(const float* __restrict__ in, bf16* __restrict__ outh,
                                  bf16* __restrict__ outl, int M, int N) {
  __shared__ float t[64][65];
  const int n0 = blockIdx.x * 64, m0 = blockIdx.y * 64;
  const long base = (long)blockIdx.z * M * N;
  const int tid = threadIdx.x;
#pragma unroll
  for (int i = 0; i < 16; ++i) {
    const int lin = i * 256 + tid;
    const int r = lin >> 6, c = lin & 63;
    t[r][c] = in[base + (long)(m0 + r) * N + (n0 + c)];
  }
  __syncthreads();
#pragma unroll
  for (int i = 0; i < 16; ++i) {
    const int lin = i * 256 + tid;
    const int r = lin >> 6, c = lin & 63;
    const float v = t[c][r];
    const long off = base + (long)(n0 + r) * M + (m0 + c);
    outh[off] = split_hi(v);
    outl[off] = split_lo(v);
  }
}

// ---- h-GEMM: A f32 (split in-kernel), Bt pre-split bf16 pair; out split-pair.
// A [M][K] f32, Bt[n][k] pair. M=1024 N=128 K=1024. BM=BN=64, 4 waves 2x2.
__global__ __launch_bounds__(256) void k_gemm_h(
    const float* __restrict__ A, const bf16* __restrict__ Bth,
    const bf16* __restrict__ Btl, bf16* __restrict__ Ch, bf16* __restrict__ Cl,
    int M, int N, int K, long sA, long sB, long sC) {
  constexpr int LDR = 40;
  __shared__ __align__(16) bf16 Ash[64 * LDR], Asl[64 * LDR];
  __shared__ __align__(16) bf16 Bsh[64 * LDR], Bsl[64 * LDR];
  const int tid = threadIdx.x, wave = tid >> 6, lane = tid & 63;
  const int quad = lane >> 4, l16 = lane & 15;
  const int wrow = wave >> 1, wcol = wave & 1;
  const int z = blockIdx.z;
  const float* Ap = A + (long)z * sA;
  const bf16* Bph = Bth + (long)z * sB;
  const bf16* Bpl = Btl + (long)z * sB;
  const long m0 = (long)blockIdx.y * 64, n0 = (long)blockIdx.x * 64;
  f32x4 acc[2][2];
#pragma unroll
  for (int mt = 0; mt < 2; ++mt)
#pragma unroll
    for (int nt = 0; nt < 2; ++nt) acc[mt][nt] = (f32x4){0.f, 0.f, 0.f, 0.f};
  for (int k0 = 0; k0 < K; k0 += 32) {
#pragma unroll
    for (int i = 0; i < 2; ++i) {
      const int c = i * 256 + tid, r = c >> 3, c4 = c & 7;
      const f32x4 v = *(const f32x4*)&Ap[(m0 + r) * K + k0 + c4 * 4];
      bf16x4 h4, l4;
#pragma unroll
      for (int j = 0; j < 4; ++j) { h4[j] = split_hi(v[j]); l4[j] = split_lo(v[j]); }
      *(bf16x4*)&Ash[r * LDR + c4 * 4] = h4;
      *(bf16x4*)&Asl[r * LDR + c4 * 4] = l4;
    }
    {
      const int r = tid >> 2, c8 = tid & 3;
      *(bf16x8*)&Bsh[r * LDR + c8 * 8] = *(const bf16x8*)&Bph[(n0 + r) * K + k0 + c8 * 8];
      *(bf16x8*)&Bsl[r * LDR + c8 * 8] = *(const bf16x8*)&Bpl[(n0 + r) * K + k0 + c8 * 8];
    }
    __syncthreads();
    bf16x8 ah[2], al[2], bh[2], bl[2];
#pragma unroll
    for (int mt = 0; mt < 2; ++mt) {
      const int row = wrow * 32 + mt * 16 + l16;
      ah[mt] = *(const bf16x8*)&Ash[row * LDR + quad * 8];
      al[mt] = *(const bf16x8*)&Asl[row * LDR + quad * 8];
    }
#pragma unroll
    for (int nt = 0; nt < 2; ++nt) {
      const int row = wcol * 32 + nt * 16 + l16;
      bh[nt] = *(const bf16x8*)&Bsh[row * LDR + quad * 8];
      bl[nt] = *(const bf16x8*)&Bsl[row * LDR + quad * 8];
    }
#pragma unroll
    for (int mt = 0; mt < 2; ++mt)
#pragma unroll
      for (int nt = 0; nt < 2; ++nt) {
        acc[mt][nt] = MFMA16(ah[mt], bh[nt], acc[mt][nt]);
        acc[mt][nt] = MFMA16(ah[mt], bl[nt], acc[mt][nt]);
        acc[mt][nt] = MFMA16(al[mt], bh[nt], acc[mt][nt]);
      }
    __syncthreads();
  }
#pragma unroll
  for (int mt = 0; mt < 2; ++mt)
#pragma unroll
    for (int nt = 0; nt < 2; ++nt)
#pragma unroll
      for (int r = 0; r < 4; ++r) {
        const long row = m0 + wrow * 32 + mt * 16 + quad * 4 + r;
        const long col = n0 + wcol * 32 + nt * 16 + l16;
        const float v = acc[mt][nt][r];
        const long off = (long)z * sC + row * (long)N + col;
        const bf16 hi = (bf16)v;
        Ch[off] = hi;
        Cl[off] = (bf16)(v - (float)hi);
      }
}

// ---- dual-bf16 GEMM: A pair [M][K], Bt pair [N][K] (both pre-split).
// SPLIT: 3 MFMAs (hh+hl+lh); else hi-only, 1 MFMA.
// mode: 0 = bf16 out, 2 = split-pair out. split_heads: C[(col/64)][row][col%64].
template <bool SPLIT>
__global__ __launch_bounds__(256) void k_gemm_dual(
    const bf16* __restrict__ Ah, const bf16* __restrict__ Al,
    const bf16* __restrict__ Bth, const bf16* __restrict__ Btl,
    bf16* __restrict__ C, bf16* __restrict__ C2, int M, int N, int K,
    long sA, long sB, long sC, int split_heads, int mode, float scale) {
  constexpr int LDR = 40;
  __shared__ __align__(16) bf16 Ash[64 * LDR], Bsh[64 * LDR];
  __shared__ __align__(16) bf16 Asl[SPLIT ? 64 * LDR : 1];
  __shared__ __align__(16) bf16 Bsl[SPLIT ? 64 * LDR : 1];
  const int tid = threadIdx.x, wave = tid >> 6, lane = tid & 63;
  const int quad = lane >> 4, l16 = lane & 15;
  const int wrow = wave >> 1, wcol = wave & 1;
  const int z = blockIdx.z;
  const bf16* Aph = Ah + (long)z * sA;
  const bf16* Apl = Al + (long)z * sA;
  const bf16* Bph = Bth + (long)z * sB;
  const bf16* Bpl = Btl + (long)z * sB;
  const long m0 = (long)blockIdx.y * 64, n0 = (long)blockIdx.x * 64;
  f32x4 acc[2][2];
#pragma unroll
  for (int mt = 0; mt < 2; ++mt)
#pragma unroll
    for (int nt = 0; nt < 2; ++nt) acc[mt][nt] = (f32x4){0.f, 0.f, 0.f, 0.f};
  for (int k0 = 0; k0 < K; k0 += 32) {
    {
      const int r = tid >> 2, c8 = tid & 3;
      *(bf16x8*)&Ash[r * LDR + c8 * 8] = *(const bf16x8*)&Aph[(m0 + r) * K + k0 + c8 * 8];
      if (SPLIT)
        *(bf16x8*)&Asl[r * LDR + c8 * 8] = *(const bf16x8*)&Apl[(m0 + r) * K + k0 + c8 * 8];
      *(bf16x8*)&Bsh[r * LDR + c8 * 8] = *(const bf16x8*)&Bph[(n0 + r) * K + k0 + c8 * 8];
      if (SPLIT)
        *(bf16x8*)&Bsl[r * LDR + c8 * 8] = *(const bf16x8*)&Bpl[(n0 + r) * K + k0 + c8 * 8];
    }
    __syncthreads();
    bf16x8 ah[2], al[2], bh[2], bl[2];
#pragma unroll
    for (int mt = 0; mt < 2; ++mt) {
      const int row = wrow * 32 + mt * 16 + l16;
      ah[mt] = *(const bf16x8*)&Ash[row * LDR + quad * 8];
      if (SPLIT) al[mt] = *(const bf16x8*)&Asl[row * LDR + quad * 8];
    }
#pragma unroll
    for (int nt = 0; nt < 2; ++nt) {
      const int row = wcol * 32 + nt * 16 + l16;
      bh[nt] = *(const bf16x8*)&Bsh[row * LDR + quad * 8];
      if (SPLIT) bl[nt] = *(const bf16x8*)&Bsl[row * LDR + quad * 8];
    }
#pragma unroll
    for (int mt = 0; mt < 2; ++mt)
#pragma unroll
      for (int nt = 0; nt < 2; ++nt) {
        acc[mt][nt] = MFMA16(ah[mt], bh[nt], acc[mt][nt]);
        if (SPLIT) {
          acc[mt][nt] = MFMA16(ah[mt], bl[nt], acc[mt][nt]);
          acc[mt][nt] = MFMA16(al[mt], bh[nt], acc[mt][nt]);
        }
      }
    __syncthreads();
  }
#pragma unroll
  for (int mt = 0; mt < 2; ++mt)
#pragma unroll
    for (int nt = 0; nt < 2; ++nt)
#pragma unroll
      for (int r = 0; r < 4; ++r) {
        const long row = m0 + wrow * 32 + mt * 16 + quad * 4 + r;
        const long col = n0 + wcol * 32 + nt * 16 + l16;
        const float v = acc[mt][nt][r] * scale;
        const long off = (long)z * sC +
                         (split_heads ? ((col >> 6) * ((long)M * 64) + row * 64 + (col & 63))
                                      : (row * (long)N + col));
        if (mode == 2) {
          const bf16 hi = (bf16)v;
          C[off] = hi;
          C2[off] = (bf16)(v - (float)hi);
        } else {
          C[off] = (bf16)v;
        }
      }
}

// ---- plain bf16 GEMM (output projection): C = A(MxK) * Bt[n][k], out f32. ----
template <int BM, int BN>
__global__ __launch_bounds__(256) void k_gemm_bt(
    const bf16* __restrict__ A, const bf16* __restrict__ Bt, float* __restrict__ C,
    int M, int N, int K) {
  constexpr int BK = 32, LDR = BK + 8;
  constexpr int MT = BM / 32, NT = BN / 32;
  __shared__ __align__(16) bf16 As[BM * LDR];
  __shared__ __align__(16) bf16 Bs[BN * LDR];
  const int tid = threadIdx.x, wave = tid >> 6, lane = tid & 63;
  const int quad = lane >> 4, l16 = lane & 15;
  const int wrow = wave >> 1, wcol = wave & 1;
  const long m0 = (long)blockIdx.y * BM, n0 = (long)blockIdx.x * BN;
  f32x4 acc[MT][NT];
#pragma unroll
  for (int mt = 0; mt < MT; ++mt)
#pragma unroll
    for (int nt = 0; nt < NT; ++nt) acc[mt][nt] = (f32x4){0.f, 0.f, 0.f, 0.f};
  constexpr int ACH = BM * BK / 8 / 256;
  constexpr int BCH = BN * BK / 8 / 256;
  for (int k0 = 0; k0 < K; k0 += BK) {
#pragma unroll
    for (int i = 0; i < ACH; ++i) {
      const int c = i * 256 + tid, r = c >> 2, c4 = c & 3;
      *(bf16x8*)&As[r * LDR + c4 * 8] = *(const bf16x8*)&A[(m0 + r) * K + k0 + c4 * 8];
    }
#pragma unroll
    for (int i = 0; i < BCH; ++i) {
      const int c = i * 256 + tid, r = c >> 2, c4 = c & 3;
      *(bf16x8*)&Bs[r * LDR + c4 * 8] = *(const bf16x8*)&Bt[(n0 + r) * K + k0 + c4 * 8];
    }
    __syncthreads();
    bf16x8 af[MT], bfr[NT];
#pragma unroll
    for (int mt = 0; mt < MT; ++mt)
      af[mt] = *(const bf16x8*)&As[(wrow * MT * 16 + mt * 16 + l16) * LDR + quad * 8];
#pragma unroll
    for (int nt = 0; nt < NT; ++nt)
      bfr[nt] = *(const bf16x8*)&Bs[(wcol * NT * 16 + nt * 16 + l16) * LDR + quad * 8];
#pragma unroll
    for (int mt = 0; mt < MT; ++mt)
#pragma unroll
      for (int nt = 0; nt < NT; ++nt)
        acc[mt][nt] = MFMA16(af[mt], bfr[nt], acc[mt][nt]);
    __syncthreads();
  }
#pragma unroll
  for (int mt = 0; mt < MT; ++mt)
#pragma unroll
    for (int nt = 0; nt < NT; ++nt)
#pragma unroll
      for (int r = 0; r < 4; ++r) {
        const long row = m0 + wrow * MT * 16 + mt * 16 + quad * 4 + r;
        const long col = n0 + wcol * NT * 16 + nt * 16 + l16;
        C[row * (long)N + col] = acc[mt][nt][r];
      }
}

// ---- causal flash attention v5: swapped QK^T + in-register softmax (as v4)
// + TWO strips per wave. 512-thread blocks, 8 waves; wave w owns strip A
// (q rows p*128+w*16, finishes after ~2p+2 chunks) and strip B
// ((7-p)*128+w*16, runs all nch chunks). Every wave does 1-2 tile_computes
// per chunk -> no barrier idling (v4: half the block idled at p=0 blocks).
// K/V staged by all 512 threads (3 bf16x8 each), issue-early/write-late,
// double-buffered. K rows stored permuted (see v4 comment) so swapped-QK
// output lands in PV B-frag order. VGPR ~90 (2 strips) -> cap 128 via
// __launch_bounds__(512,2) under either arg-2 semantics; LDS 55296 B ->
// 2 blocks/CU -> 16 waves/CU.
__global__ __launch_bounds__(512, 2) void k_attn(
    const bf16* __restrict__ Qhi, const bf16* __restrict__ Qlo,
    const bf16* __restrict__ Khi, const bf16* __restrict__ Klo,
    const bf16* __restrict__ Vtg, bf16* __restrict__ Og) {
  __shared__ __align__(16) bf16 KhiS[2 * 64 * 72], KloS[2 * 64 * 72];
  __shared__ __align__(16) bf16 VtS[2 * 64 * 72];
  const int p = blockIdx.x, bh = blockIdx.y;
  const int b = bh >> 4, hh = bh & 15;
  const int tid = threadIdx.x, wave = tid >> 6, lane = tid & 63;
  const int quad = lane >> 4, l16 = lane & 15;
  const long bhS = (long)bh * 1024 * 64;
  const bf16* KhiG = Khi + bhS;
  const bf16* KloG = Klo + bhS;
  const bf16* VtG = Vtg + (long)bh * 64 * 1024;
  const int qbwA = p * 128 + wave * 16;
  const int qbwB = (7 - p) * 128 + wave * 16;
  bf16x8 qhA[2], qlA[2], qhB[2], qlB[2];
  {
    const long rA = (long)(qbwA + l16) * 64;
    const long rB = (long)(qbwB + l16) * 64;
#pragma unroll
    for (int s = 0; s < 2; ++s) {
      qhA[s] = *(const bf16x8*)&Qhi[bhS + rA + s * 32 + quad * 8];
      qlA[s] = *(const bf16x8*)&Qlo[bhS + rA + s * 32 + quad * 8];
      qhB[s] = *(const bf16x8*)&Qhi[bhS + rB + s * 32 + quad * 8];
      qlB[s] = *(const bf16x8*)&Qlo[bhS + rB + s * 32 + quad * 8];
    }
  }
  const f32x4 zero4 = {0.f, 0.f, 0.f, 0.f};
  f32x4 oA[4], oB[4];
  float mA = -1.0e30f, lA = 0.f, mB = -1.0e30f, lB = 0.f;
#pragma unroll
  for (int nt = 0; nt < 4; ++nt) { oA[nt] = zero4; oB[nt] = zero4; }

  // staging: 512 threads each load K-hi, K-lo, Vt (one bf16x8 each; 64x64 tiles)
  const int sr = tid >> 3, sc8 = tid & 7;
  // permuted K store row: stored row pr holds true k-row k(pr) matching the
  // swapped-QK accumulation order k = s*32 + quad*8 + c*4 + r
  const int pr = ((sr >> 5) * 2 + ((sr >> 2) & 1)) * 16 + ((sr >> 3) & 3) * 4 + (sr & 3);
  bf16x8 sKh, sKl, sVt;
  auto load_regs = [&](int kc) {
    const int kb = kc * 64;
    sKh = *(const bf16x8*)&KhiG[(long)(kb + sr) * 64 + sc8 * 8];
    sKl = *(const bf16x8*)&KloG[(long)(kb + sr) * 64 + sc8 * 8];
    sVt = *(const bf16x8*)&VtG[(long)sr * 1024 + kb + sc8 * 8];
  };
  auto write_lds = [&](int buf) {
    const int ob = buf * 64 * 72;
    *(bf16x8*)&KhiS[ob + pr * 72 + sc8 * 8] = sKh;
    *(bf16x8*)&KloS[ob + pr * 72 + sc8 * 8] = sKl;
    *(bf16x8*)&VtS[ob + sr * 72 + sc8 * 8] = sVt;
  };
  auto tile_compute = [&](const bf16x8 (&qh)[2], const bf16x8 (&ql)[2],
                          f32x4 (&o)[4], float& m_i, float& l_i, int qbw,
                          int kb, int buf) {
    const int ob = buf * 64 * 72;
    f32x4 sc[4];
    __builtin_amdgcn_s_setprio(1);
#pragma unroll
    for (int ct = 0; ct < 4; ++ct) {
      const int krow = ob + (ct * 16 + l16) * 72;
      const bf16x8 kh0 = *(const bf16x8*)&KhiS[krow + quad * 8];
      const bf16x8 kh1 = *(const bf16x8*)&KhiS[krow + 32 + quad * 8];
      const bf16x8 kl0 = *(const bf16x8*)&KloS[krow + quad * 8];
      const bf16x8 kl1 = *(const bf16x8*)&KloS[krow + 32 + quad * 8];
      f32x4 s = MFMA16(kh0, qh[0], zero4);
      s = MFMA16(kh1, qh[1], s);
      s = MFMA16(kl0, qh[0], s);
      s = MFMA16(kl1, qh[1], s);
      s = MFMA16(kh0, ql[0], s);
      s = MFMA16(kh1, ql[1], s);
      sc[ct] = s;
    }
    __builtin_amdgcn_s_setprio(0);
    // lane holds S^T[k][q=qbw+l16]; true k = kb + (ct>>1)*32 + quad*8 + (ct&1)*4 + r
    const int q_glob = qbw + l16;
    if (kb + 63 > qbw) {
#pragma unroll
      for (int ct = 0; ct < 4; ++ct) {
        const int kbase = kb + (ct >> 1) * 32 + quad * 8 + (ct & 1) * 4;
#pragma unroll
        for (int r = 0; r < 4; ++r)
          if (kbase + r > q_glob) sc[ct][r] = -1.0e30f;
      }
    }
    float mx = sc[0][0];
#pragma unroll
    for (int ct = 0; ct < 4; ++ct)
#pragma unroll
      for (int r = 0; r < 4; ++r) mx = fmaxf(mx, sc[ct][r]);
    mx = fmaxf(mx, __shfl_xor(mx, 16));
    mx = fmaxf(mx, __shfl_xor(mx, 32));
    const float mnew = fmaxf(m_i, mx);
    const float alpha = __builtin_amdgcn_exp2f(m_i - mnew);
    m_i = mnew;
    float psum = 0.f;
#pragma unroll
    for (int ct = 0; ct < 4; ++ct)
#pragma unroll
      for (int r = 0; r < 4; ++r) {
        const float pv = __builtin_amdgcn_exp2f(sc[ct][r] - mnew);
        sc[ct][r] = pv;
        psum += pv;
      }
    psum += __shfl_xor(psum, 16);
    psum += __shfl_xor(psum, 32);
    l_i = l_i * alpha + psum;
#pragma unroll
    for (int nt = 0; nt < 4; ++nt)
#pragma unroll
      for (int r = 0; r < 4; ++r) o[nt][r] *= alpha;
    bf16x8 pb0, pb1;
#pragma unroll
    for (int c = 0; c < 2; ++c)
#pragma unroll
      for (int r = 0; r < 4; ++r) {
        pb0[c * 4 + r] = (bf16)sc[c][r];
        pb1[c * 4 + r] = (bf16)sc[2 + c][r];
      }
    __builtin_amdgcn_s_setprio(1);
#pragma unroll
    for (int nt = 0; nt < 4; ++nt) {
      const bf16x8 bv0 = *(const bf16x8*)&VtS[ob + (nt * 16 + l16) * 72 + quad * 8];
      const bf16x8 bv1 = *(const bf16x8*)&VtS[ob + (nt * 16 + l16) * 72 + 32 + quad * 8];
      o[nt] = MFMA16(bv0, pb0, o[nt]);
      o[nt] = MFMA16(bv1, pb1, o[nt]);
    }
    __builtin_amdgcn_s_setprio(0);
  };

  const int nch = 2 * (7 - p) + 2;
  load_regs(0);
  write_lds(0);
  __syncthreads();
  for (int kc = 0; kc < nch; ++kc) {
    const int kb = kc * 64;
    const int buf = kc & 1;
    if (kc + 1 < nch) load_regs(kc + 1);
    if (kb <= qbwA + 15) tile_compute(qhA, qlA, oA, mA, lA, qbwA, kb, buf);
    if (kb <= qbwB + 15) tile_compute(qhB, qlB, oB, mB, lB, qbwB, kb, buf);
    if (kc + 1 < nch) write_lds(1 - buf);
    __syncthreads();
  }
  // lane holds o^T[d = nt*16+quad*4+r][q = qbw+l16]
  {
    const float inv = 1.f / lA;
    const long orow = ((long)b * 1024 + qbwA + l16) * 1024 + hh * 64;
#pragma unroll
    for (int nt = 0; nt < 4; ++nt) {
      bf16x4 v4;
#pragma unroll
      for (int r = 0; r < 4; ++r) v4[r] = (bf16)(oA[nt][r] * inv);
      *(bf16x4*)&Og[orow + nt * 16 + quad * 4] = v4;
    }
  }
  {
    const float inv = 1.f / lB;
    const long orow = ((long)b * 1024 + qbwB + l16) * 1024 + hh * 64;
#pragma unroll
    for (int nt = 0; nt < 4; ++nt) {
      bf16x4 v4;
#pragma unroll
      for (int r = 0; r < 4; ++r) v4[r] = (bf16)(oB[nt][r] * inv);
      *(bf16x4*)&Og[orow + nt * 16 + quad * 4] = v4;
    }
  }
}

extern "C" void kernel_launch(void* const* d_in, const int* in_sizes, int n_in,
                              void* d_out, int out_size, void* d_ws, size_t ws_size,
                              hipStream_t stream) {
  const float* x = (const float*)d_in[0];
  const float* cw = (const float*)d_in[1];
  const int* cidx = (const int*)d_in[2];
  const float* wq = (const float*)d_in[3];
  const int* iq = (const int*)d_in[4];
  const float* wk = (const float*)d_in[5];
  const int* ik = (const int*)d_in[6];
  const float* wv = (const float*)d_in[7];
  const int* iv = (const int*)d_in[8];
  const float* neurons = (const float*)d_in[9];
  const float* pool = (const float*)d_in[10];
  const float* WO = (const float*)d_in[11];
  float* out = (float*)d_out;
  char* ws = (char*)d_ws;
  // Workspace (86 MB peak, lifetime-overlapped):
  //   [ 0,16) Khi | [16,32) Klo | [32,48) Vt (all bf16)
  //   [48,64) att bf16 -- prep overlay: Wc f32 [48,52), Wn f32 [52,64)
  //   [64,66) WcTh | [66,68) WcTl   bf16 [8][128][1024]
  //   [68,74) Wth  | [74,80) Wtl    bf16 [24][1024][128]
  //   [80,82) hh   | [82,84) hl     bf16 [8][1024][128]
  //   [84,86) WOb bf16
  //   Qhi/Qlo bf16 in d_out (2 x 16 MB), dead before the final f32 write.
  bf16* Khi = (bf16*)(ws + (0l << 20));
  bf16* Klo = (bf16*)(ws + (16l << 20));
  bf16* Vt = (bf16*)(ws + (32l << 20));
  bf16* att = (bf16*)(ws + (48l << 20));
  float* Wc = (float*)(ws + (48l << 20));
  float* Wn = (float*)(ws + (52l << 20));
  bf16* WcTh = (bf16*)(ws + (64l << 20));
  bf16* WcTl = (bf16*)(ws + (66l << 20));
  bf16* Wth = (bf16*)(ws + (68l << 20));
  bf16* Wtl = (bf16*)(ws + (74l << 20));
  bf16* hh = (bf16*)(ws + (80l << 20));
  bf16* hl = (bf16*)(ws + (82l << 20));
  bf16* WOb = (bf16*)(ws + (84l << 20));
  bf16* Qhi = (bf16*)d_out;
  bf16* Qlo = (bf16*)d_out + (8l << 20);

  k_cvt<<<1024, 256, 0, stream>>>(WO, WOb, 1024l * 1024);
  k_build_wc<<<dim3(1024, 8), 128, 0, stream>>>(neurons, cw, cidx, Wc);
  k_build_mix<<<dim3(4, 128, 24), 256, 0, stream>>>(pool, wq, iq, wk, ik, wv, iv, Wn);
  k_transpose_split<<<dim3(2, 16, 8), 256, 0, stream>>>(Wc, WcTh, WcTl, 1024, 128);
  k_transpose_split<<<dim3(16, 2, 24), 256, 0, stream>>>(Wn, Wth, Wtl, 128, 1024);
  // h = x * Wc (split A in-kernel, dual B), out split-pair hh/hl [8][1024][128]
  k_gemm_h<<<dim3(2, 16, 8), 256, 0, stream>>>(
      x, WcTh, WcTl, hh, hl, 1024, 128, 1024, 1l << 20, 1l << 17, 1l << 17);
  // Q = (h*Wq) * (log2e/8), split-pair out, head-split
  k_gemm_dual<true><<<dim3(16, 16, 8), 256, 0, stream>>>(
      hh, hl, Wth, Wtl, Qhi, Qlo, 1024, 1024, 128, 1l << 17, 1l << 17, 1l << 20,
      1, 2, 0.125f * 1.44269504088896f);
  // K split-pair out, head-split
  k_gemm_dual<true><<<dim3(16, 16, 8), 256, 0, stream>>>(
      hh, hl, Wth + (8l << 17), Wtl + (8l << 17), Khi, Klo, 1024, 1024, 128,
      1l << 17, 1l << 17, 1l << 20, 1, 2, 1.f);
  // V^T: A=Wt_V (hi only), B=h (hi only), plain bf16 out [b][d][s]
  k_gemm_dual<false><<<dim3(16, 16, 8), 256, 0, stream>>>(
      Wth + (16l << 17), nullptr, hh, nullptr, Vt, nullptr, 1024, 1024, 128,
      1l << 17, 1l << 17, 1l << 20, 0, 0, 1.f);
  k_attn<<<dim3(4, 128), 512, 0, stream>>>(Qhi, Qlo, Khi, Klo, Vt, att);
  // out(f32, 8192x1024) = att * W_O^T
  k_gemm_bt<128, 128><<<dim3(8, 64, 1), 256, 0, stream>>>(att, WOb, out, 8192, 1024, 1024);
}

// Round 6
// 324.464 us; speedup vs baseline: 1.2452x; 1.0557x over previous
//
#include <hip/hip_runtime.h>

typedef __bf16 bf16;
typedef __bf16 bf16x4 __attribute__((ext_vector_type(4)));
typedef __bf16 bf16x8 __attribute__((ext_vector_type(8)));
typedef float f32x4 __attribute__((ext_vector_type(4)));

__device__ __forceinline__ f32x4 MFMA16(bf16x8 a, bf16x8 b, f32x4 c) {
  return __builtin_amdgcn_mfma_f32_16x16x32_bf16(a, b, c, 0, 0, 0);
}

__device__ __forceinline__ bf16 split_hi(float v) { return (bf16)v; }
__device__ __forceinline__ bf16 split_lo(float v) { return (bf16)(v - (float)(bf16)v); }

// ---- fused prep: [0,1024) f32->bf16 cvt of W_O; [1024,5120) build Wc;
// [5120,17408) build Wn. Independent work, one launch (saves 2 dispatch gaps).
__global__ void k_prep(const float* __restrict__ WO, bf16* __restrict__ WOb,
                       const float* __restrict__ neurons, const float* __restrict__ cw,
                       const int* __restrict__ cidx, float* __restrict__ Wc,
                       const float* __restrict__ pool,
                       const float* __restrict__ wq, const int* __restrict__ iq,
                       const float* __restrict__ wk, const int* __restrict__ ik,
                       const float* __restrict__ wv, const int* __restrict__ iv,
                       float* __restrict__ Wn) {
  const int bid = blockIdx.x, tid = threadIdx.x;
  if (bid < 1024) {
    const long i = ((long)bid * 256 + tid) * 4;
    const f32x4 v = *(const f32x4*)&WO[i];
    bf16x4 o;
#pragma unroll
    for (int j = 0; j < 4; ++j) o[j] = (bf16)v[j];
    *(bf16x4*)&WOb[i] = o;
  } else if (bid < 5120) {
    const int wcid = bid - 1024;
    const int d = (wcid & 511) * 2 + (tid >> 7);
    const int b = wcid >> 9;
    const int r = tid & 127;
    float acc = 0.f;
#pragma unroll
    for (int k = 0; k < 16; ++k) {
      const float wkk = cw[b * 16 + k];
      const int ni = cidx[b * 16 + k];
      acc += wkk * neurons[((long)ni * 1024 + d) * 128 + r];
    }
    Wc[((long)b * 1024 + d) * 128 + r] = acc;
  } else {
    const int mid = bid - 5120;
    const int x = mid & 3;
    const int r = (mid >> 2) & 127;
    const int z = mid >> 9;  // [0,24)
    const int which = z >> 3, b = z & 7;
    const int d = x * 256 + tid;
    const float* wp = which == 0 ? wq : (which == 1 ? wk : wv);
    const int* ip = which == 0 ? iq : (which == 1 ? ik : iv);
    float acc = 0.f;
#pragma unroll
    for (int k = 0; k < 8; ++k) {
      const float wkk = wp[b * 8 + k];
      const int ni = ip[b * 8 + k];
      acc += wkk * pool[((long)ni * 128 + r) * 1024 + d];
    }
    Wn[((long)z * 128 + r) * 1024 + d] = acc;
  }
}

// ---- fused batched transpose f32 [M][N] -> split bf16 pair [N][M].
// Tiles: [0,256) = Wc (8 z, 2x16 tiles, M=1024 N=128); [256,1024) = Wn
// (24 z, 16x2 tiles, M=128 N=1024). Both strides 131072.
__global__ void k_transp(const float* __restrict__ Wc, bf16* __restrict__ WcTh,
                         bf16* __restrict__ WcTl, const float* __restrict__ Wn,
                         bf16* __restrict__ Wth, bf16* __restrict__ Wtl) {
  __shared__ float t[64][65];
  const int bid = blockIdx.x, tid = threadIdx.x;
  const float* in;
  bf16 *outh, *outl;
  int M, N, n0, m0;
  if (bid < 256) {
    const int z = bid >> 5, rem = bid & 31;
    n0 = (rem >> 4) * 64;
    m0 = (rem & 15) * 64;
    M = 1024; N = 128;
    in = Wc + (long)z * 131072;
    outh = WcTh + (long)z * 131072;
    outl = WcTl + (long)z * 131072;
  } else {
    const int tt = bid - 256;
    const int z = tt >> 5, rem = tt & 31;
    n0 = (rem & 15) * 64;
    m0 = (rem >> 4) * 64;
    M = 128; N = 1024;
    in = Wn + (long)z * 131072;
    outh = Wth + (long)z * 131072;
    outl = Wtl + (long)z * 131072;
  }
#pragma unroll
  for (int i = 0; i < 16; ++i) {
    const int lin = i * 256 + tid;
    const int r = lin >> 6, c = lin & 63;
    t[r][c] = in[(long)(m0 + r) * N + (n0 + c)];
  }
  __syncthreads();
#pragma unroll
  for (int i = 0; i < 16; ++i) {
    const int lin = i * 256 + tid;
    const int r = lin >> 6, c = lin & 63;
    const float v = t[c][r];
    const long off = (long)(n0 + r) * M + (m0 + c);
    outh[off] = split_hi(v);
    outl[off] = split_lo(v);
  }
}

// ---- h-GEMM: A f32 (split in-kernel), Bt pre-split bf16 pair; out split-pair.
// A [M][K] f32, Bt[n][k] pair. M=1024 N=128 K=1024. BM=BN=64, 4 waves 2x2.
__global__ __launch_bounds__(256) void k_gemm_h(
    const float* __restrict__ A, const bf16* __restrict__ Bth,
    const bf16* __restrict__ Btl, bf16* __restrict__ Ch, bf16* __restrict__ Cl,
    int M, int N, int K, long sA, long sB, long sC) {
  constexpr int LDR = 40;
  __shared__ __align__(16) bf16 Ash[64 * LDR], Asl[64 * LDR];
  __shared__ __align__(16) bf16 Bsh[64 * LDR], Bsl[64 * LDR];
  const int tid = threadIdx.x, wave = tid >> 6, lane = tid & 63;
  const int quad = lane >> 4, l16 = lane & 15;
  const int wrow = wave >> 1, wcol = wave & 1;
  const int z = blockIdx.z;
  const float* Ap = A + (long)z * sA;
  const bf16* Bph = Bth + (long)z * sB;
  const bf16* Bpl = Btl + (long)z * sB;
  const long m0 = (long)blockIdx.y * 64, n0 = (long)blockIdx.x * 64;
  f32x4 acc[2][2];
#pragma unroll
  for (int mt = 0; mt < 2; ++mt)
#pragma unroll
    for (int nt = 0; nt < 2; ++nt) acc[mt][nt] = (f32x4){0.f, 0.f, 0.f, 0.f};
  for (int k0 = 0; k0 < K; k0 += 32) {
#pragma unroll
    for (int i = 0; i < 2; ++i) {
      const int c = i * 256 + tid, r = c >> 3, c4 = c & 7;
      const f32x4 v = *(const f32x4*)&Ap[(m0 + r) * K + k0 + c4 * 4];
      bf16x4 h4, l4;
#pragma unroll
      for (int j = 0; j < 4; ++j) { h4[j] = split_hi(v[j]); l4[j] = split_lo(v[j]); }
      *(bf16x4*)&Ash[r * LDR + c4 * 4] = h4;
      *(bf16x4*)&Asl[r * LDR + c4 * 4] = l4;
    }
    {
      const int r = tid >> 2, c8 = tid & 3;
      *(bf16x8*)&Bsh[r * LDR + c8 * 8] = *(const bf16x8*)&Bph[(n0 + r) * K + k0 + c8 * 8];
      *(bf16x8*)&Bsl[r * LDR + c8 * 8] = *(const bf16x8*)&Bpl[(n0 + r) * K + k0 + c8 * 8];
    }
    __syncthreads();
    bf16x8 ah[2], al[2], bh[2], bl[2];
#pragma unroll
    for (int mt = 0; mt < 2; ++mt) {
      const int row = wrow * 32 + mt * 16 + l16;
      ah[mt] = *(const bf16x8*)&Ash[row * LDR + quad * 8];
      al[mt] = *(const bf16x8*)&Asl[row * LDR + quad * 8];
    }
#pragma unroll
    for (int nt = 0; nt < 2; ++nt) {
      const int row = wcol * 32 + nt * 16 + l16;
      bh[nt] = *(const bf16x8*)&Bsh[row * LDR + quad * 8];
      bl[nt] = *(const bf16x8*)&Bsl[row * LDR + quad * 8];
    }
#pragma unroll
    for (int mt = 0; mt < 2; ++mt)
#pragma unroll
      for (int nt = 0; nt < 2; ++nt) {
        acc[mt][nt] = MFMA16(ah[mt], bh[nt], acc[mt][nt]);
        acc[mt][nt] = MFMA16(ah[mt], bl[nt], acc[mt][nt]);
        acc[mt][nt] = MFMA16(al[mt], bh[nt], acc[mt][nt]);
      }
    __syncthreads();
  }
#pragma unroll
  for (int mt = 0; mt < 2; ++mt)
#pragma unroll
    for (int nt = 0; nt < 2; ++nt)
#pragma unroll
      for (int r = 0; r < 4; ++r) {
        const long row = m0 + wrow * 32 + mt * 16 + quad * 4 + r;
        const long col = n0 + wcol * 32 + nt * 16 + l16;
        const float v = acc[mt][nt][r];
        const long off = (long)z * sC + row * (long)N + col;
        const bf16 hi = (bf16)v;
        Ch[off] = hi;
        Cl[off] = (bf16)(v - (float)hi);
      }
}

// ---- fused Q/K/V projection GEMM, one launch, grid z=24.
// z in [0,16): split-pair path (3 MFMAs), A = h (split), B = Wth+z<<17,
//   out (z<8 ? Q : K) split-pair, head-split, scale (z<8 ? qscale : 1).
// z in [16,24): V^T path (1 MFMA), A = Wt_V = Wth+z<<17 (hi only), B = h (hi),
//   out Vt plain bf16 [b][d][s].
// M=N=1024, K=128. BM=BN=64, 4 waves 2x2. All selection is wave-uniform.
__global__ __launch_bounds__(256) void k_gemm_qkv(
    const bf16* __restrict__ hh, const bf16* __restrict__ hl,
    const bf16* __restrict__ Wth, const bf16* __restrict__ Wtl,
    bf16* __restrict__ Qhi, bf16* __restrict__ Qlo, bf16* __restrict__ Khi,
    bf16* __restrict__ Klo, bf16* __restrict__ Vt, float qscale) {
  constexpr int LDR = 40;
  constexpr int N = 1024, K = 128;
  __shared__ __align__(16) bf16 Ash[64 * LDR], Bsh[64 * LDR];
  __shared__ __align__(16) bf16 Asl[64 * LDR], Bsl[64 * LDR];
  const int tid = threadIdx.x, wave = tid >> 6, lane = tid & 63;
  const int quad = lane >> 4, l16 = lane & 15;
  const int wrow = wave >> 1, wcol = wave & 1;
  const int z = blockIdx.z;
  const bool sp = z < 16;
  const bf16 *Aph, *Apl, *Bph, *Bpl;
  bf16 *C, *C2;
  int heads;
  float scale;
  if (sp) {
    Aph = hh + ((long)(z & 7) << 17);
    Apl = hl + ((long)(z & 7) << 17);
    Bph = Wth + ((long)z << 17);
    Bpl = Wtl + ((long)z << 17);
    C = (z < 8 ? Qhi : Khi) + ((long)(z & 7) << 20);
    C2 = (z < 8 ? Qlo : Klo) + ((long)(z & 7) << 20);
    heads = 1;
    scale = z < 8 ? qscale : 1.f;
  } else {
    Aph = Wth + ((long)z << 17);
    Apl = nullptr;
    Bph = hh + ((long)(z - 16) << 17);
    Bpl = nullptr;
    C = Vt + ((long)(z - 16) << 20);
    C2 = nullptr;
    heads = 0;
    scale = 1.f;
  }
  const long m0 = (long)blockIdx.y * 64, n0 = (long)blockIdx.x * 64;
  f32x4 acc[2][2];
#pragma unroll
  for (int mt = 0; mt < 2; ++mt)
#pragma unroll
    for (int nt = 0; nt < 2; ++nt) acc[mt][nt] = (f32x4){0.f, 0.f, 0.f, 0.f};
  for (int k0 = 0; k0 < K; k0 += 32) {
    {
      const int r = tid >> 2, c8 = tid & 3;
      *(bf16x8*)&Ash[r * LDR + c8 * 8] = *(const bf16x8*)&Aph[(m0 + r) * K + k0 + c8 * 8];
      if (sp)
        *(bf16x8*)&Asl[r * LDR + c8 * 8] = *(const bf16x8*)&Apl[(m0 + r) * K + k0 + c8 * 8];
      *(bf16x8*)&Bsh[r * LDR + c8 * 8] = *(const bf16x8*)&Bph[(n0 + r) * K + k0 + c8 * 8];
      if (sp)
        *(bf16x8*)&Bsl[r * LDR + c8 * 8] = *(const bf16x8*)&Bpl[(n0 + r) * K + k0 + c8 * 8];
    }
    __syncthreads();
    bf16x8 ah[2], al[2], bh[2], bl[2];
#pragma unroll
    for (int mt = 0; mt < 2; ++mt) {
      const int row = wrow * 32 + mt * 16 + l16;
      ah[mt] = *(const bf16x8*)&Ash[row * LDR + quad * 8];
      if (sp) al[mt] = *(const bf16x8*)&Asl[row * LDR + quad * 8];
    }
#pragma unroll
    for (int nt = 0; nt < 2; ++nt) {
      const int row = wcol * 32 + nt * 16 + l16;
      bh[nt] = *(const bf16x8*)&Bsh[row * LDR + quad * 8];
      if (sp) bl[nt] = *(const bf16x8*)&Bsl[row * LDR + quad * 8];
    }
#pragma unroll
    for (int mt = 0; mt < 2; ++mt)
#pragma unroll
      for (int nt = 0; nt < 2; ++nt) {
        acc[mt][nt] = MFMA16(ah[mt], bh[nt], acc[mt][nt]);
        if (sp) {
          acc[mt][nt] = MFMA16(ah[mt], bl[nt], acc[mt][nt]);
          acc[mt][nt] = MFMA16(al[mt], bh[nt], acc[mt][nt]);
        }
      }
    __syncthreads();
  }
#pragma unroll
  for (int mt = 0; mt < 2; ++mt)
#pragma unroll
    for (int nt = 0; nt < 2; ++nt)
#pragma unroll
      for (int r = 0; r < 4; ++r) {
        const long row = m0 + wrow * 32 + mt * 16 + quad * 4 + r;
        const long col = n0 + wcol * 32 + nt * 16 + l16;
        const float v = acc[mt][nt][r] * scale;
        const long off = heads ? ((col >> 6) * ((long)1024 * 64) + row * 64 + (col & 63))
                               : (row * (long)N + col);
        if (sp) {
          const bf16 hi = (bf16)v;
          C[off] = hi;
          C2[off] = (bf16)(v - (float)hi);
        } else {
          C[off] = (bf16)v;
        }
      }
}

// ---- plain bf16 GEMM (output projection): C = A(MxK) * Bt[n][k], out f32. ----
template <int BM, int BN>
__global__ __launch_bounds__(256) void k_gemm_bt(
    const bf16* __restrict__ A, const bf16* __restrict__ Bt, float* __restrict__ C,
    int M, int N, int K) {
  constexpr int BK = 32, LDR = BK + 8;
  constexpr int MT = BM / 32, NT = BN / 32;
  __shared__ __align__(16) bf16 As[BM * LDR];
  __shared__ __align__(16) bf16 Bs[BN * LDR];
  const int tid = threadIdx.x, wave = tid >> 6, lane = tid & 63;
  const int quad = lane >> 4, l16 = lane & 15;
  const int wrow = wave >> 1, wcol = wave & 1;
  const long m0 = (long)blockIdx.y * BM, n0 = (long)blockIdx.x * BN;
  f32x4 acc[MT][NT];
#pragma unroll
  for (int mt = 0; mt < MT; ++mt)
#pragma unroll
    for (int nt = 0; nt < NT; ++nt) acc[mt][nt] = (f32x4){0.f, 0.f, 0.f, 0.f};
  constexpr int ACH = BM * BK / 8 / 256;
  constexpr int BCH = BN * BK / 8 / 256;
  for (int k0 = 0; k0 < K; k0 += BK) {
#pragma unroll
    for (int i = 0; i < ACH; ++i) {
      const int c = i * 256 + tid, r = c >> 2, c4 = c & 3;
      *(bf16x8*)&As[r * LDR + c4 * 8] = *(const bf16x8*)&A[(m0 + r) * K + k0 + c4 * 8];
    }
#pragma unroll
    for (int i = 0; i < BCH; ++i) {
      const int c = i * 256 + tid, r = c >> 2, c4 = c & 3;
      *(bf16x8*)&Bs[r * LDR + c4 * 8] = *(const bf16x8*)&Bt[(n0 + r) * K + k0 + c4 * 8];
    }
    __syncthreads();
    bf16x8 af[MT], bfr[NT];
#pragma unroll
    for (int mt = 0; mt < MT; ++mt)
      af[mt] = *(const bf16x8*)&As[(wrow * MT * 16 + mt * 16 + l16) * LDR + quad * 8];
#pragma unroll
    for (int nt = 0; nt < NT; ++nt)
      bfr[nt] = *(const bf16x8*)&Bs[(wcol * NT * 16 + nt * 16 + l16) * LDR + quad * 8];
#pragma unroll
    for (int mt = 0; mt < MT; ++mt)
#pragma unroll
      for (int nt = 0; nt < NT; ++nt)
        acc[mt][nt] = MFMA16(af[mt], bfr[nt], acc[mt][nt]);
    __syncthreads();
  }
#pragma unroll
  for (int mt = 0; mt < MT; ++mt)
#pragma unroll
    for (int nt = 0; nt < NT; ++nt)
#pragma unroll
      for (int r = 0; r < 4; ++r) {
        const long row = m0 + wrow * MT * 16 + mt * 16 + quad * 4 + r;
        const long col = n0 + wcol * NT * 16 + nt * 16 + l16;
        C[row * (long)N + col] = acc[mt][nt][r];
      }
}

// ---- causal flash attention v6: v5 (swapped QK^T, in-register softmax, two
// strips per wave) + shared K/V fragment loads: both strips consume the SAME
// kh/kl/bv LDS fragments, so chunk_compute loads each once and feeds both
// (v5 re-read all 24 b128s per strip; ~28% of DS reads were duplicates).
__global__ __launch_bounds__(512, 2) void k_attn(
    const bf16* __restrict__ Qhi, const bf16* __restrict__ Qlo,
    const bf16* __restrict__ Khi, const bf16* __restrict__ Klo,
    const bf16* __restrict__ Vtg, bf16* __restrict__ Og) {
  __shared__ __align__(16) bf16 KhiS[2 * 64 * 72], KloS[2 * 64 * 72];
  __shared__ __align__(16) bf16 VtS[2 * 64 * 72];
  const int p = blockIdx.x, bh = blockIdx.y;
  const int b = bh >> 4, hh = bh & 15;
  const int tid = threadIdx.x, wave = tid >> 6, lane = tid & 63;
  const int quad = lane >> 4, l16 = lane & 15;
  const long bhS = (long)bh * 1024 * 64;
  const bf16* KhiG = Khi + bhS;
  const bf16* KloG = Klo + bhS;
  const bf16* VtG = Vtg + (long)bh * 64 * 1024;
  const int qbwA = p * 128 + wave * 16;
  const int qbwB = (7 - p) * 128 + wave * 16;
  bf16x8 qhA[2], qlA[2], qhB[2], qlB[2];
  {
    const long rA = (long)(qbwA + l16) * 64;
    const long rB = (long)(qbwB + l16) * 64;
#pragma unroll
    for (int s = 0; s < 2; ++s) {
      qhA[s] = *(const bf16x8*)&Qhi[bhS + rA + s * 32 + quad * 8];
      qlA[s] = *(const bf16x8*)&Qlo[bhS + rA + s * 32 + quad * 8];
      qhB[s] = *(const bf16x8*)&Qhi[bhS + rB + s * 32 + quad * 8];
      qlB[s] = *(const bf16x8*)&Qlo[bhS + rB + s * 32 + quad * 8];
    }
  }
  const f32x4 zero4 = {0.f, 0.f, 0.f, 0.f};
  f32x4 oA[4], oB[4];
  float mA = -1.0e30f, lA = 0.f, mB = -1.0e30f, lB = 0.f;
#pragma unroll
  for (int nt = 0; nt < 4; ++nt) { oA[nt] = zero4; oB[nt] = zero4; }

  // staging: 512 threads each load K-hi, K-lo, Vt (one bf16x8 each; 64x64 tiles)
  const int sr = tid >> 3, sc8 = tid & 7;
  // permuted K store row: stored row pr holds true k-row matching the
  // swapped-QK accumulation order k = s*32 + quad*8 + c*4 + r
  const int pr = ((sr >> 5) * 2 + ((sr >> 2) & 1)) * 16 + ((sr >> 3) & 3) * 4 + (sr & 3);
  bf16x8 sKh, sKl, sVt;
  auto load_regs = [&](int kc) {
    const int kb = kc * 64;
    sKh = *(const bf16x8*)&KhiG[(long)(kb + sr) * 64 + sc8 * 8];
    sKl = *(const bf16x8*)&KloG[(long)(kb + sr) * 64 + sc8 * 8];
    sVt = *(const bf16x8*)&VtG[(long)sr * 1024 + kb + sc8 * 8];
  };
  auto write_lds = [&](int buf) {
    const int ob = buf * 64 * 72;
    *(bf16x8*)&KhiS[ob + pr * 72 + sc8 * 8] = sKh;
    *(bf16x8*)&KloS[ob + pr * 72 + sc8 * 8] = sKl;
    *(bf16x8*)&VtS[ob + sr * 72 + sc8 * 8] = sVt;
  };
  auto softmax_pack = [&](f32x4 (&sc)[4], f32x4 (&o)[4], float& m_i, float& l_i,
                          int qbw, int kb, bf16x8& pb0, bf16x8& pb1) {
    const int q_glob = qbw + l16;
    if (kb + 63 > qbw) {
#pragma unroll
      for (int ct = 0; ct < 4; ++ct) {
        const int kbase = kb + (ct >> 1) * 32 + quad * 8 + (ct & 1) * 4;
#pragma unroll
        for (int r = 0; r < 4; ++r)
          if (kbase + r > q_glob) sc[ct][r] = -1.0e30f;
      }
    }
    float mx = sc[0][0];
#pragma unroll
    for (int ct = 0; ct < 4; ++ct)
#pragma unroll
      for (int r = 0; r < 4; ++r) mx = fmaxf(mx, sc[ct][r]);
    mx = fmaxf(mx, __shfl_xor(mx, 16));
    mx = fmaxf(mx, __shfl_xor(mx, 32));
    const float mnew = fmaxf(m_i, mx);
    const float alpha = __builtin_amdgcn_exp2f(m_i - mnew);
    m_i = mnew;
    float psum = 0.f;
#pragma unroll
    for (int ct = 0; ct < 4; ++ct)
#pragma unroll
      for (int r = 0; r < 4; ++r) {
        const float pv = __builtin_amdgcn_exp2f(sc[ct][r] - mnew);
        sc[ct][r] = pv;
        psum += pv;
      }
    psum += __shfl_xor(psum, 16);
    psum += __shfl_xor(psum, 32);
    l_i = l_i * alpha + psum;
#pragma unroll
    for (int nt = 0; nt < 4; ++nt)
#pragma unroll
      for (int r = 0; r < 4; ++r) o[nt][r] *= alpha;
#pragma unroll
    for (int c = 0; c < 2; ++c)
#pragma unroll
      for (int r = 0; r < 4; ++r) {
        pb0[c * 4 + r] = (bf16)sc[c][r];
        pb1[c * 4 + r] = (bf16)sc[2 + c][r];
      }
  };
  auto chunk_compute = [&](int kb, int buf) {
    const bool actA = kb <= qbwA + 15;
    const bool actB = kb <= qbwB + 15;
    if (!(actA || actB)) return;
    const int ob = buf * 64 * 72;
    f32x4 scA[4], scB[4];
    __builtin_amdgcn_s_setprio(1);
#pragma unroll
    for (int ct = 0; ct < 4; ++ct) {
      const int krow = ob + (ct * 16 + l16) * 72;
      const bf16x8 kh0 = *(const bf16x8*)&KhiS[krow + quad * 8];
      const bf16x8 kh1 = *(const bf16x8*)&KhiS[krow + 32 + quad * 8];
      const bf16x8 kl0 = *(const bf16x8*)&KloS[krow + quad * 8];
      const bf16x8 kl1 = *(const bf16x8*)&KloS[krow + 32 + quad * 8];
      if (actA) {
        f32x4 s = MFMA16(kh0, qhA[0], zero4);
        s = MFMA16(kh1, qhA[1], s);
        s = MFMA16(kl0, qhA[0], s);
        s = MFMA16(kl1, qhA[1], s);
        s = MFMA16(kh0, qlA[0], s);
        s = MFMA16(kh1, qlA[1], s);
        scA[ct] = s;
      }
      if (actB) {
        f32x4 s = MFMA16(kh0, qhB[0], zero4);
        s = MFMA16(kh1, qhB[1], s);
        s = MFMA16(kl0, qhB[0], s);
        s = MFMA16(kl1, qhB[1], s);
        s = MFMA16(kh0, qlB[0], s);
        s = MFMA16(kh1, qlB[1], s);
        scB[ct] = s;
      }
    }
    __builtin_amdgcn_s_setprio(0);
    bf16x8 pA0, pA1, pB0, pB1;
    if (actA) softmax_pack(scA, oA, mA, lA, qbwA, kb, pA0, pA1);
    if (actB) softmax_pack(scB, oB, mB, lB, qbwB, kb, pB0, pB1);
    __builtin_amdgcn_s_setprio(1);
#pragma unroll
    for (int nt = 0; nt < 4; ++nt) {
      const bf16x8 bv0 = *(const bf16x8*)&VtS[ob + (nt * 16 + l16) * 72 + quad * 8];
      const bf16x8 bv1 = *(const bf16x8*)&VtS[ob + (nt * 16 + l16) * 72 + 32 + quad * 8];
      if (actA) {
        oA[nt] = MFMA16(bv0, pA0, oA[nt]);
        oA[nt] = MFMA16(bv1, pA1, oA[nt]);
      }
      if (actB) {
        oB[nt] = MFMA16(bv0, pB0, oB[nt]);
        oB[nt] = MFMA16(bv1, pB1, oB[nt]);
      }
    }
    __builtin_amdgcn_s_setprio(0);
  };

  const int nch = 2 * (7 - p) + 2;
  load_regs(0);
  write_lds(0);
  __syncthreads();
  for (int kc = 0; kc < nch; ++kc) {
    const int kb = kc * 64;
    const int buf = kc & 1;
    if (kc + 1 < nch) load_regs(kc + 1);
    chunk_compute(kb, buf);
    if (kc + 1 < nch) write_lds(1 - buf);
    __syncthreads();
  }
  // lane holds o^T[d = nt*16+quad*4+r][q = qbw+l16]
  {
    const float inv = 1.f / lA;
    const long orow = ((long)b * 1024 + qbwA + l16) * 1024 + hh * 64;
#pragma unroll
    for (int nt = 0; nt < 4; ++nt) {
      bf16x4 v4;
#pragma unroll
      for (int r = 0; r < 4; ++r) v4[r] = (bf16)(oA[nt][r] * inv);
      *(bf16x4*)&Og[orow + nt * 16 + quad * 4] = v4;
    }
  }
  {
    const float inv = 1.f / lB;
    const long orow = ((long)b * 1024 + qbwB + l16) * 1024 + hh * 64;
#pragma unroll
    for (int nt = 0; nt < 4; ++nt) {
      bf16x4 v4;
#pragma unroll
      for (int r = 0; r < 4; ++r) v4[r] = (bf16)(oB[nt][r] * inv);
      *(bf16x4*)&Og[orow + nt * 16 + quad * 4] = v4;
    }
  }
}

extern "C" void kernel_launch(void* const* d_in, const int* in_sizes, int n_in,
                              void* d_out, int out_size, void* d_ws, size_t ws_size,
                              hipStream_t stream) {
  const float* x = (const float*)d_in[0];
  const float* cw = (const float*)d_in[1];
  const int* cidx = (const int*)d_in[2];
  const float* wq = (const float*)d_in[3];
  const int* iq = (const int*)d_in[4];
  const float* wk = (const float*)d_in[5];
  const int* ik = (const int*)d_in[6];
  const float* wv = (const float*)d_in[7];
  const int* iv = (const int*)d_in[8];
  const float* neurons = (const float*)d_in[9];
  const float* pool = (const float*)d_in[10];
  const float* WO = (const float*)d_in[11];
  float* out = (float*)d_out;
  char* ws = (char*)d_ws;
  // Workspace (86 MB peak, lifetime-overlapped):
  //   [ 0,16) Khi | [16,32) Klo | [32,48) Vt (all bf16)
  //   [48,64) att bf16 -- prep overlay: Wc f32 [48,52), Wn f32 [52,64)
  //   [64,66) WcTh | [66,68) WcTl   bf16 [8][128][1024]
  //   [68,74) Wth  | [74,80) Wtl    bf16 [24][1024][128]
  //   [80,82) hh   | [82,84) hl     bf16 [8][1024][128]
  //   [84,86) WOb bf16
  //   Qhi/Qlo bf16 in d_out (2 x 16 MB), dead before the final f32 write.
  bf16* Khi = (bf16*)(ws + (0l << 20));
  bf16* Klo = (bf16*)(ws + (16l << 20));
  bf16* Vt = (bf16*)(ws + (32l << 20));
  bf16* att = (bf16*)(ws + (48l << 20));
  float* Wc = (float*)(ws + (48l << 20));
  float* Wn = (float*)(ws + (52l << 20));
  bf16* WcTh = (bf16*)(ws + (64l << 20));
  bf16* WcTl = (bf16*)(ws + (66l << 20));
  bf16* Wth = (bf16*)(ws + (68l << 20));
  bf16* Wtl = (bf16*)(ws + (74l << 20));
  bf16* hh = (bf16*)(ws + (80l << 20));
  bf16* hl = (bf16*)(ws + (82l << 20));
  bf16* WOb = (bf16*)(ws + (84l << 20));
  bf16* Qhi = (bf16*)d_out;
  bf16* Qlo = (bf16*)d_out + (8l << 20);

  // prep: cvt (1024) + build_wc (4096) + build_mix (12288) = 17408 blocks
  k_prep<<<17408, 256, 0, stream>>>(WO, WOb, neurons, cw, cidx, Wc, pool, wq, iq,
                                    wk, ik, wv, iv, Wn);
  // both transposes: 256 (Wc) + 768 (Wn) tiles
  k_transp<<<1024, 256, 0, stream>>>(Wc, WcTh, WcTl, Wn, Wth, Wtl);
  // h = x * Wc (split A in-kernel, dual B), out split-pair hh/hl [8][1024][128]
  k_gemm_h<<<dim3(2, 16, 8), 256, 0, stream>>>(
      x, WcTh, WcTl, hh, hl, 1024, 128, 1024, 1l << 20, 1l << 17, 1l << 17);
  // Q, K (split-pair, head-split) and V^T (plain) in one launch
  k_gemm_qkv<<<dim3(16, 16, 24), 256, 0, stream>>>(
      hh, hl, Wth, Wtl, Qhi, Qlo, Khi, Klo, Vt, 0.125f * 1.44269504088896f);
  k_attn<<<dim3(4, 128), 512, 0, stream>>>(Qhi, Qlo, Khi, Klo, Vt, att);
  // out(f32, 8192x1024) = att * W_O^T
  k_gemm_bt<128, 128><<<dim3(8, 64, 1), 256, 0, stream>>>(att, WOb, out, 8192, 1024, 1024);
}